// Round 4
// baseline (1333.261 us; speedup 1.0000x reference)
//
#include <hip/hip_runtime.h>
#include <math.h>

#define NN 200000
#define NE 3200000
#define NF 128
#define NG 1000
#define KSEL 30
#define CCAT 97
#define NPAD 200704      // 196 * 1024, padded node count for the scan
#define SCAN_BLKS 196

#define BWID 512                  // nodes per bucket (dst >> 9)
#define NB 391                    // ceil(NN / BWID)
#define BCAP 10240                // per-bucket edge capacity (mean 8184, sigma ~90)
#define P1_CHUNK 8192             // edges per block in partition pass
#define P1_BLKS 391               // ceil(NE / P1_CHUNK)

// ---------------- pass 1: partition edges into dst-buckets ----------------
__global__ void k_p1_partition(const int* __restrict__ ei, int* __restrict__ bcursor,
                               int* __restrict__ ebuf) {
    __shared__ int lhist[NB];
    __shared__ int lbase[NB];
    int tid = threadIdx.x;
    int base = blockIdx.x * P1_CHUNK;
    for (int b = tid; b < NB; b += 256) lhist[b] = 0;
    __syncthreads();
    for (int it = 0; it < P1_CHUNK / 256; it++) {
        int e = base + it * 256 + tid;
        if (e < NE) {
            int s = ei[e], d = ei[NE + e];
            if (s != d) atomicAdd(&lhist[d >> 9], 1);
        }
    }
    __syncthreads();
    for (int b = tid; b < NB; b += 256) {
        int cnt = lhist[b];
        lbase[b] = cnt ? atomicAdd(&bcursor[b], cnt) : 0;
        lhist[b] = 0;
    }
    __syncthreads();
    for (int it = 0; it < P1_CHUNK / 256; it++) {
        int e = base + it * 256 + tid;
        if (e < NE) {
            int s = ei[e], d = ei[NE + e];
            if (s != d) {
                int b = d >> 9;
                int r = atomicAdd(&lhist[b], 1);
                int pos = lbase[b] + r;
                if (pos >= BCAP) pos = BCAP - 1;  // defensive (cannot happen)
                ebuf[b * BCAP + pos] = s | ((d & 511) << 18);
            }
        }
    }
}

// ---------------- pass 2: per-bucket node counts (coalesced) + inv_sqrt ----------------
__global__ void k_p2_count(const int* __restrict__ bcursor, const int* __restrict__ ebuf,
                           int* __restrict__ rowcnt, float* __restrict__ inv_sqrt) {
    __shared__ int lcnt[BWID];
    int b = blockIdx.x;
    int tid = threadIdx.x;
    for (int i = tid; i < BWID; i += 256) lcnt[i] = 0;
    __syncthreads();
    int size = bcursor[b];
    if (size > BCAP) size = BCAP;
    const int* eb = ebuf + b * BCAP;
    for (int k = tid; k < size; k += 256) atomicAdd(&lcnt[eb[k] >> 18], 1);
    __syncthreads();
    int node0 = b * BWID;
    for (int i = tid; i < BWID; i += 256) {
        int node = node0 + i;
        if (node < NN) {
            int c = lcnt[i];
            rowcnt[node] = c;
            inv_sqrt[node] = rsqrtf((float)(c + 1));
        }
    }
}

// ---------------- scan (rowcnt -> rowstart, exclusive) ----------------
__global__ void k_scanA(const int* __restrict__ in, int* __restrict__ out,
                        int* __restrict__ bsums) {
    __shared__ int s[1024];
    int tid = threadIdx.x;
    int gid = blockIdx.x * 1024 + tid;
    int v = in[gid];
    s[tid] = v;
    __syncthreads();
    for (int off = 1; off < 1024; off <<= 1) {
        int a = (tid >= off) ? s[tid - off] : 0;
        int cur = s[tid];
        __syncthreads();
        s[tid] = cur + a;
        __syncthreads();
    }
    out[gid] = s[tid] - v;
    if (tid == 1023) bsums[blockIdx.x] = s[tid];
}

__global__ void k_scanB(int* __restrict__ bsums) {
    __shared__ int s[256];
    int tid = threadIdx.x;
    int v = (tid < SCAN_BLKS) ? bsums[tid] : 0;
    s[tid] = v;
    __syncthreads();
    for (int off = 1; off < 256; off <<= 1) {
        int a = (tid >= off) ? s[tid - off] : 0;
        int cur = s[tid];
        __syncthreads();
        s[tid] = cur + a;
        __syncthreads();
    }
    if (tid < SCAN_BLKS) bsums[tid] = s[tid] - v;
}

__global__ void k_scanC(int* __restrict__ out, const int* __restrict__ bsums) {
    int gid = blockIdx.x * 1024 + threadIdx.x;
    out[gid] += bsums[blockIdx.x];
}

// ---------------- pass 3: bucket -> CSR esrc (writes localized per block) ----------------
__global__ void k_p3_scatter(const int* __restrict__ bcursor, const int* __restrict__ ebuf,
                             const int* __restrict__ rowstart, int* __restrict__ esrc) {
    __shared__ int lcur[BWID];
    int b = blockIdx.x;
    int tid = threadIdx.x;
    int node0 = b * BWID;
    for (int i = tid; i < BWID; i += 256) lcur[i] = rowstart[node0 + i];
    __syncthreads();
    int size = bcursor[b];
    if (size > BCAP) size = BCAP;
    const int* eb = ebuf + b * BCAP;
    for (int k = tid; k < size; k += 256) {
        int v = eb[k];
        int local = v >> 18;
        int pos = atomicAdd(&lcur[local], 1);
        esrc[pos] = v & 0x3FFFF;
    }
}

// ---------------- dense matmul: hws[n,32] = (X[n,K] @ W[K,32]) * inv_sqrt[n] ----------------
// Micro-tiled 4 rows x 4 channels per thread; W broadcast from LDS.
// Explicit 2-deep software pipeline on the X loads: cur/next register sets,
// next-next loads issued BEFORE the FMA block -> 8 float4 loads in flight/wave.
template <int K>
__global__ void __launch_bounds__(256, 6) k_mm(const float* __restrict__ X,
                                               const float* __restrict__ W,
                                               const float* __restrict__ inv_sqrt,
                                               float* __restrict__ Y) {
    __shared__ float4 sW[K * 8];   // sW[k*8+q] = W[k][4q..4q+3]
    int tid = threadIdx.x;
    for (int i = tid; i < K * 8; i += 256) sW[i] = ((const float4*)W)[i];
    __syncthreads();
    int g = tid >> 3;              // row-group (0..31)
    int q = tid & 7;               // channel quad (c = 4q..4q+3)
    int r0 = blockIdx.x * 128 + g * 4;
    if (r0 >= NN) return;          // NN % 4 == 0, whole group valid or not
    const float4* __restrict__ xp0 = (const float4*)(X + (size_t)(r0 + 0) * K);
    const float4* __restrict__ xp1 = (const float4*)(X + (size_t)(r0 + 1) * K);
    const float4* __restrict__ xp2 = (const float4*)(X + (size_t)(r0 + 2) * K);
    const float4* __restrict__ xp3 = (const float4*)(X + (size_t)(r0 + 3) * K);
    constexpr int NK = K / 4;      // >= 8 for K in {32,128}
    float4 a0 = make_float4(0.f, 0.f, 0.f, 0.f);
    float4 a1 = make_float4(0.f, 0.f, 0.f, 0.f);
    float4 a2 = make_float4(0.f, 0.f, 0.f, 0.f);
    float4 a3 = make_float4(0.f, 0.f, 0.f, 0.f);
    float4 c0 = xp0[0], c1 = xp1[0], c2 = xp2[0], c3 = xp3[0];
    float4 n0 = xp0[1], n1 = xp1[1], n2 = xp2[1], n3 = xp3[1];
#pragma unroll 4
    for (int k4 = 0; k4 < NK; k4++) {
        float4 x0 = c0, x1 = c1, x2 = c2, x3 = c3;
        c0 = n0; c1 = n1; c2 = n2; c3 = n3;
        int kn = k4 + 2;
        if (kn < NK) { n0 = xp0[kn]; n1 = xp1[kn]; n2 = xp2[kn]; n3 = xp3[kn]; }
        const float4* wk = &sW[k4 * 32 + q];
#pragma unroll
        for (int kk = 0; kk < 4; kk++) {
            float4 w = wk[kk * 8];
            float s0 = (kk == 0) ? x0.x : (kk == 1) ? x0.y : (kk == 2) ? x0.z : x0.w;
            float s1 = (kk == 0) ? x1.x : (kk == 1) ? x1.y : (kk == 2) ? x1.z : x1.w;
            float s2 = (kk == 0) ? x2.x : (kk == 1) ? x2.y : (kk == 2) ? x2.z : x2.w;
            float s3 = (kk == 0) ? x3.x : (kk == 1) ? x3.y : (kk == 2) ? x3.z : x3.w;
            a0.x = fmaf(s0, w.x, a0.x); a0.y = fmaf(s0, w.y, a0.y);
            a0.z = fmaf(s0, w.z, a0.z); a0.w = fmaf(s0, w.w, a0.w);
            a1.x = fmaf(s1, w.x, a1.x); a1.y = fmaf(s1, w.y, a1.y);
            a1.z = fmaf(s1, w.z, a1.z); a1.w = fmaf(s1, w.w, a1.w);
            a2.x = fmaf(s2, w.x, a2.x); a2.y = fmaf(s2, w.y, a2.y);
            a2.z = fmaf(s2, w.z, a2.z); a2.w = fmaf(s2, w.w, a2.w);
            a3.x = fmaf(s3, w.x, a3.x); a3.y = fmaf(s3, w.y, a3.y);
            a3.z = fmaf(s3, w.z, a3.z); a3.w = fmaf(s3, w.w, a3.w);
        }
    }
    float s0 = inv_sqrt[r0 + 0];
    float s1 = inv_sqrt[r0 + 1];
    float s2 = inv_sqrt[r0 + 2];
    float s3 = inv_sqrt[r0 + 3];
    a0.x *= s0; a0.y *= s0; a0.z *= s0; a0.w *= s0;
    a1.x *= s1; a1.y *= s1; a1.z *= s1; a1.w *= s1;
    a2.x *= s2; a2.y *= s2; a2.z *= s2; a2.w *= s2;
    a3.x *= s3; a3.y *= s3; a3.z *= s3; a3.w *= s3;
    ((float4*)(Y + (size_t)(r0 + 0) * 32))[q] = a0;
    ((float4*)(Y + (size_t)(r0 + 1) * 32))[q] = a1;
    ((float4*)(Y + (size_t)(r0 + 2) * 32))[q] = a2;
    ((float4*)(Y + (size_t)(r0 + 3) * 32))[q] = a3;
}

// ---------------- gather-aggregate ----------------
// Half-wave (32 lanes) per node: lane = slot(0..3) x quad(0..7); each lane
// gathers a float4. Main block = 16 edges: 4 independent esrc loads then
// 4 independent gathers (16 lines in flight/wave) into dual accumulators.
__global__ void k_aggr(const int* __restrict__ rowstart, const int* __restrict__ esrc,
                       const float* __restrict__ hws, const float* __restrict__ inv_sqrt,
                       const float* __restrict__ b, float* __restrict__ xout) {
    int t = blockIdx.x * 256 + threadIdx.x;
    int n = t >> 5;
    if (n >= NN) return;
    int l = threadIdx.x & 31;
    int slot = l >> 3;             // 0..3 : edge slot
    int q = l & 7;                 // 0..7 : channel quad
    const float4* __restrict__ hp = (const float4*)hws;
    int e0 = rowstart[n], e1 = rowstart[n + 1];
    float4 aA = make_float4(0.f, 0.f, 0.f, 0.f);
    float4 aB = make_float4(0.f, 0.f, 0.f, 0.f);
    int e = e0;
    for (; e + 16 <= e1; e += 16) {
        int i0 = esrc[e + slot];
        int i1 = esrc[e + 4 + slot];
        int i2 = esrc[e + 8 + slot];
        int i3 = esrc[e + 12 + slot];
        float4 v0 = hp[i0 * 8 + q];
        float4 v1 = hp[i1 * 8 + q];
        float4 v2 = hp[i2 * 8 + q];
        float4 v3 = hp[i3 * 8 + q];
        aA.x += v0.x; aA.y += v0.y; aA.z += v0.z; aA.w += v0.w;
        aB.x += v1.x; aB.y += v1.y; aB.z += v1.z; aB.w += v1.w;
        aA.x += v2.x; aA.y += v2.y; aA.z += v2.z; aA.w += v2.w;
        aB.x += v3.x; aB.y += v3.y; aB.z += v3.z; aB.w += v3.w;
    }
    for (; e + 4 <= e1; e += 4) {
        int i0 = esrc[e + slot];
        float4 v = hp[i0 * 8 + q];
        aA.x += v.x; aA.y += v.y; aA.z += v.z; aA.w += v.w;
    }
    int rem = e1 - e;              // 0..3
    if (slot < rem) {
        int i0 = esrc[e + slot];
        float4 v = hp[i0 * 8 + q];
        aB.x += v.x; aB.y += v.y; aB.z += v.z; aB.w += v.w;
    }
    float4 acc;
    acc.x = aA.x + aB.x; acc.y = aA.y + aB.y;
    acc.z = aA.z + aB.z; acc.w = aA.w + aB.w;
    // reduce across the 4 slots (lane bits 3 and 4)
    acc.x += __shfl_xor(acc.x, 8);
    acc.y += __shfl_xor(acc.y, 8);
    acc.z += __shfl_xor(acc.z, 8);
    acc.w += __shfl_xor(acc.w, 8);
    acc.x += __shfl_xor(acc.x, 16);
    acc.y += __shfl_xor(acc.y, 16);
    acc.z += __shfl_xor(acc.z, 16);
    acc.w += __shfl_xor(acc.w, 16);
    if (slot == 0) {
        float4 self = hp[n * 8 + q];
        float4 bq = ((const float4*)b)[q];
        float is = inv_sqrt[n];
        float4 r;
        r.x = tanhf(fmaf(acc.x + self.x, is, bq.x));
        r.y = tanhf(fmaf(acc.y + self.y, is, bq.y));
        r.z = tanhf(fmaf(acc.z + self.z, is, bq.z));
        r.w = tanhf(fmaf(acc.w + self.w, is, bq.w));
        ((float4*)(xout + (size_t)n * 32))[q] = r;
    }
}

// layer 4: hws4[n] = (x3[n,:] . W4) * inv_sqrt[n]
__global__ void k_mm4(const float* __restrict__ x3, const float* __restrict__ W4,
                      const float* __restrict__ inv_sqrt, float* __restrict__ hws4) {
    int n = blockIdx.x * 256 + threadIdx.x;
    if (n >= NN) return;
    const float4* xr = (const float4*)(x3 + (size_t)n * 32);
    float acc = 0.0f;
#pragma unroll
    for (int q = 0; q < 8; q++) {
        float4 v = xr[q];
        acc = fmaf(v.x, W4[q * 4 + 0], acc);
        acc = fmaf(v.y, W4[q * 4 + 1], acc);
        acc = fmaf(v.z, W4[q * 4 + 2], acc);
        acc = fmaf(v.w, W4[q * 4 + 3], acc);
    }
    hws4[n] = acc * inv_sqrt[n];
}

// layer-4 aggregation (1 channel), 8-wide ILP
__global__ void k_aggr1(const int* __restrict__ rowstart, const int* __restrict__ esrc,
                        const float* __restrict__ hws4, const float* __restrict__ inv_sqrt,
                        const float* __restrict__ b4, float* __restrict__ x4) {
    int n = blockIdx.x * 256 + threadIdx.x;
    if (n >= NN) return;
    int e0 = rowstart[n], e1 = rowstart[n + 1];
    float a[8];
    a[0] = hws4[n];
#pragma unroll
    for (int k = 1; k < 8; k++) a[k] = 0.0f;
    for (int e = e0; e < e1; e += 8) {
        int ss[8];
#pragma unroll
        for (int k = 0; k < 8; k++) ss[k] = esrc[(e + k < e1) ? e + k : e];
        float vv[8];
#pragma unroll
        for (int k = 0; k < 8; k++) vv[k] = hws4[ss[k]];
        a[0] += vv[0];
#pragma unroll
        for (int k = 1; k < 8; k++) a[k] += (e + k < e1) ? vv[k] : 0.0f;
    }
    float acc = ((a[0] + a[1]) + (a[2] + a[3])) + ((a[4] + a[5]) + (a[6] + a[7]));
    x4[n] = tanhf(fmaf(acc, inv_sqrt[n], b4[0]));
}

// ---------------- graph boundaries from sorted batch (no atomics) ----------------
// starts[g] = first node index with batch[n] >= g; starts[NG] = NN
__global__ void k_gbounds(const int* __restrict__ batch, int* __restrict__ starts) {
    int n = blockIdx.x * 256 + threadIdx.x;
    if (n >= NN) return;
    int bn = batch[n];
    int bp = (n == 0) ? -1 : batch[n - 1];
    for (int g = bp + 1; g <= bn; g++) starts[g] = n;
    if (n == NN - 1)
        for (int g = bn + 1; g <= NG; g++) starts[g] = NN;
}

__global__ void k_sortpool(const int* __restrict__ starts,
                           const float* __restrict__ x1, const float* __restrict__ x2,
                           const float* __restrict__ x3, const float* __restrict__ x4,
                           float* __restrict__ pooled) {
    __shared__ float keys[1024];
    __shared__ int sel[KSEL];
    int g = blockIdx.x;
    int tid = threadIdx.x;
    int start = starts[g];
    int cnt = starts[g + 1] - start;
    if (cnt > 1024) cnt = 1024;
    for (int i = tid; i < cnt; i += 256) keys[i] = x4[start + i];
    __syncthreads();
    for (int i = tid; i < cnt; i += 256) {
        float ki = keys[i];
        int rank = 0;
        for (int j = 0; j < cnt; j++) {
            float kj = keys[j];
            rank += (kj > ki) || (kj == ki && j < i);  // stable desc, matches lexsort
        }
        if (rank < KSEL) sel[rank] = start + i;
    }
    __syncthreads();
    int selcnt = cnt < KSEL ? cnt : KSEL;
    for (int t = tid; t < KSEL * CCAT; t += 256) {
        int r = t / CCAT, ch = t - r * CCAT;
        float v = 0.0f;
        if (r < selcnt) {
            int node = sel[r];
            if (ch < 32)      v = x1[(size_t)node * 32 + ch];
            else if (ch < 64) v = x2[(size_t)node * 32 + ch - 32];
            else if (ch < 96) v = x3[(size_t)node * 32 + ch - 64];
            else              v = x4[node];
        }
        pooled[g * (KSEL * CCAT) + t] = v;
    }
}

// ---------------- CNN + MLP head, one block per graph ----------------
__global__ void k_head(const float* __restrict__ pooled,
                       const float* __restrict__ w5, const float* __restrict__ b5,
                       const float* __restrict__ w6, const float* __restrict__ b6,
                       const float* __restrict__ fw1, const float* __restrict__ fb1,
                       const float* __restrict__ fw2, const float* __restrict__ fb2,
                       float* __restrict__ out) {
    __shared__ float sP[KSEL * CCAT];
    __shared__ float s5[16 * 30];
    __shared__ float smp[16 * 15];
    __shared__ float sz[352];
    __shared__ float sh[128];
    __shared__ float sl[10];
    int g = blockIdx.x;
    int tid = threadIdx.x;
    for (int i = tid; i < KSEL * CCAT; i += 256) sP[i] = pooled[g * (KSEL * CCAT) + i];
    __syncthreads();
    for (int t = tid; t < 16 * 30; t += 256) {
        int c = t / 30, j = t - c * 30;
        float acc = b5[c];
        for (int i = 0; i < CCAT; i++) acc = fmaf(sP[j * CCAT + i], w5[c * CCAT + i], acc);
        s5[c * 30 + j] = fmaxf(acc, 0.0f);
    }
    __syncthreads();
    for (int t = tid; t < 16 * 15; t += 256) {
        int c = t / 15, j = t - c * 15;
        smp[t] = fmaxf(s5[c * 30 + 2 * j], s5[c * 30 + 2 * j + 1]);
    }
    __syncthreads();
    for (int t = tid; t < 32 * 11; t += 256) {
        int c = t / 11, j = t - c * 11;
        float acc = b6[c];
        for (int ci = 0; ci < 16; ci++) {
#pragma unroll
            for (int k = 0; k < 5; k++)
                acc = fmaf(smp[ci * 15 + j + k], w6[(c * 16 + ci) * 5 + k], acc);
        }
        sz[t] = fmaxf(acc, 0.0f);
    }
    __syncthreads();
    if (tid < 128) {
        float acc = fb1[tid];
        for (int i = 0; i < 352; i++) acc = fmaf(sz[i], fw1[i * 128 + tid], acc);
        sh[tid] = fmaxf(acc, 0.0f);
    }
    __syncthreads();
    if (tid < 10) {
        float acc = fb2[tid];
        for (int i = 0; i < 128; i++) acc = fmaf(sh[i], fw2[i * 10 + tid], acc);
        sl[tid] = acc;
    }
    __syncthreads();
    if (tid < 10) {
        float m = -1e30f;
        for (int i = 0; i < 10; i++) m = fmaxf(m, sl[i]);
        float ssum = 0.0f;
        for (int i = 0; i < 10; i++) ssum += expf(sl[i] - m);
        out[g * 10 + tid] = sl[tid] - m - logf(ssum);
    }
}

extern "C" void kernel_launch(void* const* d_in, const int* in_sizes, int n_in,
                              void* d_out, int out_size, void* d_ws, size_t ws_size,
                              hipStream_t stream) {
    const float* x   = (const float*)d_in[0];
    const int*   ei  = (const int*)d_in[1];
    const int*   bat = (const int*)d_in[2];
    const float* W1  = (const float*)d_in[3];
    const float* b1  = (const float*)d_in[4];
    const float* W2  = (const float*)d_in[5];
    const float* b2  = (const float*)d_in[6];
    const float* W3  = (const float*)d_in[7];
    const float* b3  = (const float*)d_in[8];
    const float* W4  = (const float*)d_in[9];
    const float* b4  = (const float*)d_in[10];
    const float* w5  = (const float*)d_in[11];
    const float* b5  = (const float*)d_in[12];
    const float* w6  = (const float*)d_in[13];
    const float* b6  = (const float*)d_in[14];
    const float* fw1 = (const float*)d_in[15];
    const float* fb1 = (const float*)d_in[16];
    const float* fw2 = (const float*)d_in[17];
    const float* fb2 = (const float*)d_in[18];
    float* out = (float*)d_out;

    float* ws = (float*)d_ws;
    float* inv_sqrt = ws;                          // NN
    float* hws      = inv_sqrt + NN;               // NN*32 (also hws4 in first NN)
    float* x1       = hws + (size_t)NN * 32;       // NN*32
    float* x2       = x1 + (size_t)NN * 32;        // NN*32
    float* x3       = x2 + (size_t)NN * 32;        // NN*32
    float* x4       = x3 + (size_t)NN * 32;       // NN
    float* pooled   = x4 + NN;                     // NG*KSEL*CCAT
    int* rowcnt     = (int*)(pooled + NG * KSEL * CCAT);  // NPAD
    int* rowstart   = rowcnt + NPAD;               // NPAD
    int* esrc       = rowstart + NPAD;             // NE
    int* bcursor    = esrc + NE;                   // NB (pad to 512)
    int* bsums      = bcursor + 512;               // 256
    int* gstarts    = bsums + 256;                 // NG+1 (pad to 1024)
    int* ebuf       = (int*)x3;                    // NB*BCAP ints (16 MB), dead before x3 written

    const int TB = 256;
    int gN  = (NN + TB - 1) / TB;
    int gNC = (NN * 32 + TB - 1) / TB;
    int gMM = (NN + 127) / 128;    // 128 rows per block in k_mm

    // ---- CSR build via bucketed partition ----
    hipMemsetAsync(bcursor, 0, 512 * sizeof(int), stream);
    hipMemsetAsync(rowcnt, 0, NPAD * sizeof(int), stream);
    k_p1_partition<<<P1_BLKS, TB, 0, stream>>>(ei, bcursor, ebuf);
    k_p2_count<<<NB, TB, 0, stream>>>(bcursor, ebuf, rowcnt, inv_sqrt);
    k_scanA<<<SCAN_BLKS, 1024, 0, stream>>>(rowcnt, rowstart, bsums);
    k_scanB<<<1, 256, 0, stream>>>(bsums);
    k_scanC<<<SCAN_BLKS, 1024, 0, stream>>>(rowstart, bsums);
    k_p3_scatter<<<NB, TB, 0, stream>>>(bcursor, ebuf, rowstart, esrc);

    // ---- graph boundaries (sorted batch -> no atomics) ----
    k_gbounds<<<gN, TB, 0, stream>>>(bat, gstarts);

    // ---- GCN layers ----
    k_mm<128><<<gMM, TB, 0, stream>>>(x, W1, inv_sqrt, hws);
    k_aggr<<<gNC, TB, 0, stream>>>(rowstart, esrc, hws, inv_sqrt, b1, x1);
    k_mm<32><<<gMM, TB, 0, stream>>>(x1, W2, inv_sqrt, hws);
    k_aggr<<<gNC, TB, 0, stream>>>(rowstart, esrc, hws, inv_sqrt, b2, x2);
    k_mm<32><<<gMM, TB, 0, stream>>>(x2, W3, inv_sqrt, hws);
    k_aggr<<<gNC, TB, 0, stream>>>(rowstart, esrc, hws, inv_sqrt, b3, x3);
    k_mm4<<<gN, TB, 0, stream>>>(x3, W4, inv_sqrt, hws);
    k_aggr1<<<gN, TB, 0, stream>>>(rowstart, esrc, hws, inv_sqrt, b4, x4);

    // ---- sort-pool + head ----
    k_sortpool<<<NG, TB, 0, stream>>>(gstarts, x1, x2, x3, x4, pooled);
    k_head<<<NG, TB, 0, stream>>>(pooled, w5, b5, w6, b6, fw1, fb1, fw2, fb2, out);
}

// Round 5
// 601.420 us; speedup vs baseline: 2.2169x; 2.2169x over previous
//
#include <hip/hip_runtime.h>
#include <math.h>

#define NN 200000
#define NE 3200000
#define NF 128
#define NG 1000
#define KSEL 30
#define CCAT 97
#define NPAD 200704      // 196 * 1024, padded node count for the scan
#define SCAN_BLKS 196

#define BWID 512                  // nodes per bucket (dst >> 9)
#define NB 391                    // ceil(NN / BWID)
#define BCAP 10240                // per-bucket edge capacity (mean 8184, sigma ~90)
#define P1_CHUNK 8192             // edges per block in partition pass
#define P1_BLKS 391               // ceil(NE / P1_CHUNK)

// ---------------- pass 1: partition edges into dst-buckets ----------------
__global__ void k_p1_partition(const int* __restrict__ ei, int* __restrict__ bcursor,
                               int* __restrict__ ebuf) {
    __shared__ int lhist[NB];
    __shared__ int lbase[NB];
    int tid = threadIdx.x;
    int base = blockIdx.x * P1_CHUNK;
    for (int b = tid; b < NB; b += 256) lhist[b] = 0;
    __syncthreads();
    for (int it = 0; it < P1_CHUNK / 256; it++) {
        int e = base + it * 256 + tid;
        if (e < NE) {
            int s = ei[e], d = ei[NE + e];
            if (s != d) atomicAdd(&lhist[d >> 9], 1);
        }
    }
    __syncthreads();
    for (int b = tid; b < NB; b += 256) {
        int cnt = lhist[b];
        lbase[b] = cnt ? atomicAdd(&bcursor[b], cnt) : 0;
        lhist[b] = 0;
    }
    __syncthreads();
    for (int it = 0; it < P1_CHUNK / 256; it++) {
        int e = base + it * 256 + tid;
        if (e < NE) {
            int s = ei[e], d = ei[NE + e];
            if (s != d) {
                int b = d >> 9;
                int r = atomicAdd(&lhist[b], 1);
                int pos = lbase[b] + r;
                if (pos >= BCAP) pos = BCAP - 1;  // defensive (cannot happen)
                ebuf[b * BCAP + pos] = s | ((d & 511) << 18);
            }
        }
    }
}

// ---------------- pass 2: per-bucket node counts (coalesced) + inv_sqrt ----------------
__global__ void k_p2_count(const int* __restrict__ bcursor, const int* __restrict__ ebuf,
                           int* __restrict__ rowcnt, float* __restrict__ inv_sqrt) {
    __shared__ int lcnt[BWID];
    int b = blockIdx.x;
    int tid = threadIdx.x;
    for (int i = tid; i < BWID; i += 256) lcnt[i] = 0;
    __syncthreads();
    int size = bcursor[b];
    if (size > BCAP) size = BCAP;
    const int* eb = ebuf + b * BCAP;
    for (int k = tid; k < size; k += 256) atomicAdd(&lcnt[eb[k] >> 18], 1);
    __syncthreads();
    int node0 = b * BWID;
    for (int i = tid; i < BWID; i += 256) {
        int node = node0 + i;
        if (node < NN) {
            int c = lcnt[i];
            rowcnt[node] = c;
            inv_sqrt[node] = rsqrtf((float)(c + 1));
        }
    }
}

// ---------------- scan (rowcnt -> rowstart, exclusive) ----------------
__global__ void k_scanA(const int* __restrict__ in, int* __restrict__ out,
                        int* __restrict__ bsums) {
    __shared__ int s[1024];
    int tid = threadIdx.x;
    int gid = blockIdx.x * 1024 + tid;
    int v = in[gid];
    s[tid] = v;
    __syncthreads();
    for (int off = 1; off < 1024; off <<= 1) {
        int a = (tid >= off) ? s[tid - off] : 0;
        int cur = s[tid];
        __syncthreads();
        s[tid] = cur + a;
        __syncthreads();
    }
    out[gid] = s[tid] - v;
    if (tid == 1023) bsums[blockIdx.x] = s[tid];
}

__global__ void k_scanB(int* __restrict__ bsums) {
    __shared__ int s[256];
    int tid = threadIdx.x;
    int v = (tid < SCAN_BLKS) ? bsums[tid] : 0;
    s[tid] = v;
    __syncthreads();
    for (int off = 1; off < 256; off <<= 1) {
        int a = (tid >= off) ? s[tid - off] : 0;
        int cur = s[tid];
        __syncthreads();
        s[tid] = cur + a;
        __syncthreads();
    }
    if (tid < SCAN_BLKS) bsums[tid] = s[tid] - v;
}

__global__ void k_scanC(int* __restrict__ out, const int* __restrict__ bsums) {
    int gid = blockIdx.x * 1024 + threadIdx.x;
    out[gid] += bsums[blockIdx.x];
}

// ---------------- pass 3: bucket -> CSR esrc (writes localized per block) ----------------
__global__ void k_p3_scatter(const int* __restrict__ bcursor, const int* __restrict__ ebuf,
                             const int* __restrict__ rowstart, int* __restrict__ esrc) {
    __shared__ int lcur[BWID];
    int b = blockIdx.x;
    int tid = threadIdx.x;
    int node0 = b * BWID;
    for (int i = tid; i < BWID; i += 256) lcur[i] = rowstart[node0 + i];
    __syncthreads();
    int size = bcursor[b];
    if (size > BCAP) size = BCAP;
    const int* eb = ebuf + b * BCAP;
    for (int k = tid; k < size; k += 256) {
        int v = eb[k];
        int local = v >> 18;
        int pos = atomicAdd(&lcur[local], 1);
        esrc[pos] = v & 0x3FFFF;
    }
}

// ---------------- dense matmul: hws[n,32] = (X[n,K] @ W[K,32]) * inv_sqrt[n] ----------------
// Micro-tiled: each thread computes 4 rows x 4 channels; W broadcast from LDS.
// 128-thread blocks, 64 rows each -> 3125 blocks, ~10 blocks/CU (LDS cap) =
// 20 waves/CU for latency hiding (was grid-limited at ~13 with 256-thread blocks).
// Inner loop identical to the proven round-2 codegen (VGPR 36, no spills).
template <int K>
__global__ void __launch_bounds__(128, 5) k_mm(const float* __restrict__ X,
                                               const float* __restrict__ W,
                                               const float* __restrict__ inv_sqrt,
                                               float* __restrict__ Y) {
    __shared__ float4 sW[K * 8];   // sW[k*8+q] = W[k][4q..4q+3]
    int tid = threadIdx.x;
    for (int i = tid; i < K * 8; i += 128) sW[i] = ((const float4*)W)[i];
    __syncthreads();
    int g = tid >> 3;              // row-group (0..15)
    int q = tid & 7;               // channel quad (c = 4q..4q+3)
    int r0 = blockIdx.x * 64 + g * 4;
    if (r0 >= NN) return;          // NN % 4 == 0, whole group valid or not
    const float4* __restrict__ xp0 = (const float4*)(X + (size_t)(r0 + 0) * K);
    const float4* __restrict__ xp1 = (const float4*)(X + (size_t)(r0 + 1) * K);
    const float4* __restrict__ xp2 = (const float4*)(X + (size_t)(r0 + 2) * K);
    const float4* __restrict__ xp3 = (const float4*)(X + (size_t)(r0 + 3) * K);
    float4 a0 = make_float4(0.f, 0.f, 0.f, 0.f);
    float4 a1 = make_float4(0.f, 0.f, 0.f, 0.f);
    float4 a2 = make_float4(0.f, 0.f, 0.f, 0.f);
    float4 a3 = make_float4(0.f, 0.f, 0.f, 0.f);
#pragma unroll 2
    for (int k4 = 0; k4 < K / 4; k4++) {
        float4 x0 = xp0[k4];
        float4 x1 = xp1[k4];
        float4 x2 = xp2[k4];
        float4 x3 = xp3[k4];
        const float4* wk = &sW[k4 * 32 + q];
#pragma unroll
        for (int kk = 0; kk < 4; kk++) {
            float4 w = wk[kk * 8];
            float s0 = (kk == 0) ? x0.x : (kk == 1) ? x0.y : (kk == 2) ? x0.z : x0.w;
            float s1 = (kk == 0) ? x1.x : (kk == 1) ? x1.y : (kk == 2) ? x1.z : x1.w;
            float s2 = (kk == 0) ? x2.x : (kk == 1) ? x2.y : (kk == 2) ? x2.z : x2.w;
            float s3 = (kk == 0) ? x3.x : (kk == 1) ? x3.y : (kk == 2) ? x3.z : x3.w;
            a0.x = fmaf(s0, w.x, a0.x); a0.y = fmaf(s0, w.y, a0.y);
            a0.z = fmaf(s0, w.z, a0.z); a0.w = fmaf(s0, w.w, a0.w);
            a1.x = fmaf(s1, w.x, a1.x); a1.y = fmaf(s1, w.y, a1.y);
            a1.z = fmaf(s1, w.z, a1.z); a1.w = fmaf(s1, w.w, a1.w);
            a2.x = fmaf(s2, w.x, a2.x); a2.y = fmaf(s2, w.y, a2.y);
            a2.z = fmaf(s2, w.z, a2.z); a2.w = fmaf(s2, w.w, a2.w);
            a3.x = fmaf(s3, w.x, a3.x); a3.y = fmaf(s3, w.y, a3.y);
            a3.z = fmaf(s3, w.z, a3.z); a3.w = fmaf(s3, w.w, a3.w);
        }
    }
    float s0 = inv_sqrt[r0 + 0];
    float s1 = inv_sqrt[r0 + 1];
    float s2 = inv_sqrt[r0 + 2];
    float s3 = inv_sqrt[r0 + 3];
    a0.x *= s0; a0.y *= s0; a0.z *= s0; a0.w *= s0;
    a1.x *= s1; a1.y *= s1; a1.z *= s1; a1.w *= s1;
    a2.x *= s2; a2.y *= s2; a2.z *= s2; a2.w *= s2;
    a3.x *= s3; a3.y *= s3; a3.z *= s3; a3.w *= s3;
    ((float4*)(Y + (size_t)(r0 + 0) * 32))[q] = a0;
    ((float4*)(Y + (size_t)(r0 + 1) * 32))[q] = a1;
    ((float4*)(Y + (size_t)(r0 + 2) * 32))[q] = a2;
    ((float4*)(Y + (size_t)(r0 + 3) * 32))[q] = a3;
}

// ---------------- gather-aggregate, 8-wide ILP, 32 channels/node ----------------
// (proven round-0/2 version: 16 cache lines in flight per wave)
__global__ void k_aggr(const int* __restrict__ rowstart, const int* __restrict__ esrc,
                       const float* __restrict__ hws, const float* __restrict__ inv_sqrt,
                       const float* __restrict__ b, float* __restrict__ xout) {
    int t = blockIdx.x * 256 + threadIdx.x;
    int n = t >> 5, c = t & 31;
    if (n >= NN) return;
    int e0 = rowstart[n], e1 = rowstart[n + 1];
    float a[8];
    a[0] = hws[(size_t)n * 32 + c];
#pragma unroll
    for (int k = 1; k < 8; k++) a[k] = 0.0f;
    for (int e = e0; e < e1; e += 8) {
        int ss[8];
#pragma unroll
        for (int k = 0; k < 8; k++) ss[k] = esrc[(e + k < e1) ? e + k : e];
        float vv[8];
#pragma unroll
        for (int k = 0; k < 8; k++) vv[k] = hws[(size_t)ss[k] * 32 + c];
        a[0] += vv[0];
#pragma unroll
        for (int k = 1; k < 8; k++) a[k] += (e + k < e1) ? vv[k] : 0.0f;
    }
    float acc = ((a[0] + a[1]) + (a[2] + a[3])) + ((a[4] + a[5]) + (a[6] + a[7]));
    xout[t] = tanhf(fmaf(acc, inv_sqrt[n], b[c]));
}

// layer 4: hws4[n] = (x3[n,:] . W4) * inv_sqrt[n]
__global__ void k_mm4(const float* __restrict__ x3, const float* __restrict__ W4,
                      const float* __restrict__ inv_sqrt, float* __restrict__ hws4) {
    int n = blockIdx.x * 256 + threadIdx.x;
    if (n >= NN) return;
    const float4* xr = (const float4*)(x3 + (size_t)n * 32);
    float acc = 0.0f;
#pragma unroll
    for (int q = 0; q < 8; q++) {
        float4 v = xr[q];
        acc = fmaf(v.x, W4[q * 4 + 0], acc);
        acc = fmaf(v.y, W4[q * 4 + 1], acc);
        acc = fmaf(v.z, W4[q * 4 + 2], acc);
        acc = fmaf(v.w, W4[q * 4 + 3], acc);
    }
    hws4[n] = acc * inv_sqrt[n];
}

// layer-4 aggregation (1 channel), 8-wide ILP
__global__ void k_aggr1(const int* __restrict__ rowstart, const int* __restrict__ esrc,
                        const float* __restrict__ hws4, const float* __restrict__ inv_sqrt,
                        const float* __restrict__ b4, float* __restrict__ x4) {
    int n = blockIdx.x * 256 + threadIdx.x;
    if (n >= NN) return;
    int e0 = rowstart[n], e1 = rowstart[n + 1];
    float a[8];
    a[0] = hws4[n];
#pragma unroll
    for (int k = 1; k < 8; k++) a[k] = 0.0f;
    for (int e = e0; e < e1; e += 8) {
        int ss[8];
#pragma unroll
        for (int k = 0; k < 8; k++) ss[k] = esrc[(e + k < e1) ? e + k : e];
        float vv[8];
#pragma unroll
        for (int k = 0; k < 8; k++) vv[k] = hws4[ss[k]];
        a[0] += vv[0];
#pragma unroll
        for (int k = 1; k < 8; k++) a[k] += (e + k < e1) ? vv[k] : 0.0f;
    }
    float acc = ((a[0] + a[1]) + (a[2] + a[3])) + ((a[4] + a[5]) + (a[6] + a[7]));
    x4[n] = tanhf(fmaf(acc, inv_sqrt[n], b4[0]));
}

// ---------------- graph boundaries from sorted batch (no atomics) ----------------
// starts[g] = first node index with batch[n] >= g; starts[NG] = NN
__global__ void k_gbounds(const int* __restrict__ batch, int* __restrict__ starts) {
    int n = blockIdx.x * 256 + threadIdx.x;
    if (n >= NN) return;
    int bn = batch[n];
    int bp = (n == 0) ? -1 : batch[n - 1];
    for (int g = bp + 1; g <= bn; g++) starts[g] = n;
    if (n == NN - 1)
        for (int g = bn + 1; g <= NG; g++) starts[g] = NN;
}

__global__ void k_sortpool(const int* __restrict__ starts,
                           const float* __restrict__ x1, const float* __restrict__ x2,
                           const float* __restrict__ x3, const float* __restrict__ x4,
                           float* __restrict__ pooled) {
    __shared__ float keys[1024];
    __shared__ int sel[KSEL];
    int g = blockIdx.x;
    int tid = threadIdx.x;
    int start = starts[g];
    int cnt = starts[g + 1] - start;
    if (cnt > 1024) cnt = 1024;
    for (int i = tid; i < cnt; i += 256) keys[i] = x4[start + i];
    __syncthreads();
    for (int i = tid; i < cnt; i += 256) {
        float ki = keys[i];
        int rank = 0;
        for (int j = 0; j < cnt; j++) {
            float kj = keys[j];
            rank += (kj > ki) || (kj == ki && j < i);  // stable desc, matches lexsort
        }
        if (rank < KSEL) sel[rank] = start + i;
    }
    __syncthreads();
    int selcnt = cnt < KSEL ? cnt : KSEL;
    for (int t = tid; t < KSEL * CCAT; t += 256) {
        int r = t / CCAT, ch = t - r * CCAT;
        float v = 0.0f;
        if (r < selcnt) {
            int node = sel[r];
            if (ch < 32)      v = x1[(size_t)node * 32 + ch];
            else if (ch < 64) v = x2[(size_t)node * 32 + ch - 32];
            else if (ch < 96) v = x3[(size_t)node * 32 + ch - 64];
            else              v = x4[node];
        }
        pooled[g * (KSEL * CCAT) + t] = v;
    }
}

// ---------------- CNN + MLP head, one block per graph ----------------
__global__ void k_head(const float* __restrict__ pooled,
                       const float* __restrict__ w5, const float* __restrict__ b5,
                       const float* __restrict__ w6, const float* __restrict__ b6,
                       const float* __restrict__ fw1, const float* __restrict__ fb1,
                       const float* __restrict__ fw2, const float* __restrict__ fb2,
                       float* __restrict__ out) {
    __shared__ float sP[KSEL * CCAT];
    __shared__ float s5[16 * 30];
    __shared__ float smp[16 * 15];
    __shared__ float sz[352];
    __shared__ float sh[128];
    __shared__ float sl[10];
    int g = blockIdx.x;
    int tid = threadIdx.x;
    for (int i = tid; i < KSEL * CCAT; i += 256) sP[i] = pooled[g * (KSEL * CCAT) + i];
    __syncthreads();
    for (int t = tid; t < 16 * 30; t += 256) {
        int c = t / 30, j = t - c * 30;
        float acc = b5[c];
        for (int i = 0; i < CCAT; i++) acc = fmaf(sP[j * CCAT + i], w5[c * CCAT + i], acc);
        s5[c * 30 + j] = fmaxf(acc, 0.0f);
    }
    __syncthreads();
    for (int t = tid; t < 16 * 15; t += 256) {
        int c = t / 15, j = t - c * 15;
        smp[t] = fmaxf(s5[c * 30 + 2 * j], s5[c * 30 + 2 * j + 1]);
    }
    __syncthreads();
    for (int t = tid; t < 32 * 11; t += 256) {
        int c = t / 11, j = t - c * 11;
        float acc = b6[c];
        for (int ci = 0; ci < 16; ci++) {
#pragma unroll
            for (int k = 0; k < 5; k++)
                acc = fmaf(smp[ci * 15 + j + k], w6[(c * 16 + ci) * 5 + k], acc);
        }
        sz[t] = fmaxf(acc, 0.0f);
    }
    __syncthreads();
    if (tid < 128) {
        float acc = fb1[tid];
        for (int i = 0; i < 352; i++) acc = fmaf(sz[i], fw1[i * 128 + tid], acc);
        sh[tid] = fmaxf(acc, 0.0f);
    }
    __syncthreads();
    if (tid < 10) {
        float acc = fb2[tid];
        for (int i = 0; i < 128; i++) acc = fmaf(sh[i], fw2[i * 10 + tid], acc);
        sl[tid] = acc;
    }
    __syncthreads();
    if (tid < 10) {
        float m = -1e30f;
        for (int i = 0; i < 10; i++) m = fmaxf(m, sl[i]);
        float ssum = 0.0f;
        for (int i = 0; i < 10; i++) ssum += expf(sl[i] - m);
        out[g * 10 + tid] = sl[tid] - m - logf(ssum);
    }
}

extern "C" void kernel_launch(void* const* d_in, const int* in_sizes, int n_in,
                              void* d_out, int out_size, void* d_ws, size_t ws_size,
                              hipStream_t stream) {
    const float* x   = (const float*)d_in[0];
    const int*   ei  = (const int*)d_in[1];
    const int*   bat = (const int*)d_in[2];
    const float* W1  = (const float*)d_in[3];
    const float* b1  = (const float*)d_in[4];
    const float* W2  = (const float*)d_in[5];
    const float* b2  = (const float*)d_in[6];
    const float* W3  = (const float*)d_in[7];
    const float* b3  = (const float*)d_in[8];
    const float* W4  = (const float*)d_in[9];
    const float* b4  = (const float*)d_in[10];
    const float* w5  = (const float*)d_in[11];
    const float* b5  = (const float*)d_in[12];
    const float* w6  = (const float*)d_in[13];
    const float* b6  = (const float*)d_in[14];
    const float* fw1 = (const float*)d_in[15];
    const float* fb1 = (const float*)d_in[16];
    const float* fw2 = (const float*)d_in[17];
    const float* fb2 = (const float*)d_in[18];
    float* out = (float*)d_out;

    float* ws = (float*)d_ws;
    float* inv_sqrt = ws;                          // NN
    float* hws      = inv_sqrt + NN;               // NN*32 (also hws4 in first NN)
    float* x1       = hws + (size_t)NN * 32;       // NN*32
    float* x2       = x1 + (size_t)NN * 32;        // NN*32
    float* x3       = x2 + (size_t)NN * 32;        // NN*32
    float* x4       = x3 + (size_t)NN * 32;       // NN
    float* pooled   = x4 + NN;                     // NG*KSEL*CCAT
    int* rowcnt     = (int*)(pooled + NG * KSEL * CCAT);  // NPAD
    int* rowstart   = rowcnt + NPAD;               // NPAD
    int* esrc       = rowstart + NPAD;             // NE
    int* bcursor    = esrc + NE;                   // NB (pad to 512)
    int* bsums      = bcursor + 512;               // 256
    int* gstarts    = bsums + 256;                 // NG+1 (pad to 1024)
    int* ebuf       = (int*)x3;                    // NB*BCAP ints (16 MB), dead before x3 written

    const int TB = 256;
    int gN  = (NN + TB - 1) / TB;
    int gNC = (NN * 32 + TB - 1) / TB;
    int gMM = (NN + 63) / 64;      // 64 rows per 128-thread block in k_mm

    // ---- CSR build via bucketed partition ----
    hipMemsetAsync(bcursor, 0, 512 * sizeof(int), stream);
    hipMemsetAsync(rowcnt, 0, NPAD * sizeof(int), stream);
    k_p1_partition<<<P1_BLKS, TB, 0, stream>>>(ei, bcursor, ebuf);
    k_p2_count<<<NB, TB, 0, stream>>>(bcursor, ebuf, rowcnt, inv_sqrt);
    k_scanA<<<SCAN_BLKS, 1024, 0, stream>>>(rowcnt, rowstart, bsums);
    k_scanB<<<1, 256, 0, stream>>>(bsums);
    k_scanC<<<SCAN_BLKS, 1024, 0, stream>>>(rowstart, bsums);
    k_p3_scatter<<<NB, TB, 0, stream>>>(bcursor, ebuf, rowstart, esrc);

    // ---- graph boundaries (sorted batch -> no atomics) ----
    k_gbounds<<<gN, TB, 0, stream>>>(bat, gstarts);

    // ---- GCN layers ----
    k_mm<128><<<gMM, 128, 0, stream>>>(x, W1, inv_sqrt, hws);
    k_aggr<<<gNC, TB, 0, stream>>>(rowstart, esrc, hws, inv_sqrt, b1, x1);
    k_mm<32><<<gMM, 128, 0, stream>>>(x1, W2, inv_sqrt, hws);
    k_aggr<<<gNC, TB, 0, stream>>>(rowstart, esrc, hws, inv_sqrt, b2, x2);
    k_mm<32><<<gMM, 128, 0, stream>>>(x2, W3, inv_sqrt, hws);
    k_aggr<<<gNC, TB, 0, stream>>>(rowstart, esrc, hws, inv_sqrt, b3, x3);
    k_mm4<<<gN, TB, 0, stream>>>(x3, W4, inv_sqrt, hws);
    k_aggr1<<<gN, TB, 0, stream>>>(rowstart, esrc, hws, inv_sqrt, b4, x4);

    // ---- sort-pool + head ----
    k_sortpool<<<NG, TB, 0, stream>>>(gstarts, x1, x2, x3, x4, pooled);
    k_head<<<NG, TB, 0, stream>>>(pooled, w5, b5, w6, b6, fw1, fb1, fw2, fb2, out);
}

// Round 6
// 599.760 us; speedup vs baseline: 2.2230x; 1.0028x over previous
//
#include <hip/hip_runtime.h>
#include <math.h>

#define NN 200000
#define NE 3200000
#define NF 128
#define NG 1000
#define KSEL 30
#define CCAT 97
#define NPAD 200704      // 196 * 1024, padded node count for the scan
#define SCAN_BLKS 196
#define EPADCAP (NE + 8 * NN)     // padded-CSR esrc capacity

#define BWID 512                  // nodes per bucket (dst >> 9)
#define NB 391                    // ceil(NN / BWID)
#define BCAP 10240                // per-bucket edge capacity (mean 8184, sigma ~90)
#define P1_CHUNK 8192             // edges per block in partition pass
#define P1_BLKS 391               // ceil(NE / P1_CHUNK)

// ---------------- pass 1: partition edges into dst-buckets ----------------
__global__ void k_p1_partition(const int* __restrict__ ei, int* __restrict__ bcursor,
                               int* __restrict__ ebuf) {
    __shared__ int lhist[NB];
    __shared__ int lbase[NB];
    int tid = threadIdx.x;
    int base = blockIdx.x * P1_CHUNK;
    for (int b = tid; b < NB; b += 256) lhist[b] = 0;
    __syncthreads();
    for (int it = 0; it < P1_CHUNK / 256; it++) {
        int e = base + it * 256 + tid;
        if (e < NE) {
            int s = ei[e], d = ei[NE + e];
            if (s != d) atomicAdd(&lhist[d >> 9], 1);
        }
    }
    __syncthreads();
    for (int b = tid; b < NB; b += 256) {
        int cnt = lhist[b];
        lbase[b] = cnt ? atomicAdd(&bcursor[b], cnt) : 0;
        lhist[b] = 0;
    }
    __syncthreads();
    for (int it = 0; it < P1_CHUNK / 256; it++) {
        int e = base + it * 256 + tid;
        if (e < NE) {
            int s = ei[e], d = ei[NE + e];
            if (s != d) {
                int b = d >> 9;
                int r = atomicAdd(&lhist[b], 1);
                int pos = lbase[b] + r;
                if (pos >= BCAP) pos = BCAP - 1;  // defensive (cannot happen)
                ebuf[b * BCAP + pos] = s | ((d & 511) << 18);
            }
        }
    }
}

// ---------------- pass 2: per-bucket node counts + inv_sqrt ----------------
// rowcnt gets the count PADDED to a multiple of 8 (for conditional-free aggr);
// inv_sqrt uses the real count.
__global__ void k_p2_count(const int* __restrict__ bcursor, const int* __restrict__ ebuf,
                           int* __restrict__ rowcnt, float* __restrict__ inv_sqrt) {
    __shared__ int lcnt[BWID];
    int b = blockIdx.x;
    int tid = threadIdx.x;
    for (int i = tid; i < BWID; i += 256) lcnt[i] = 0;
    __syncthreads();
    int size = bcursor[b];
    if (size > BCAP) size = BCAP;
    const int* eb = ebuf + b * BCAP;
    for (int k = tid; k < size; k += 256) atomicAdd(&lcnt[eb[k] >> 18], 1);
    __syncthreads();
    int node0 = b * BWID;
    for (int i = tid; i < BWID; i += 256) {
        int node = node0 + i;
        if (node < NN) {
            int c = lcnt[i];
            rowcnt[node] = (c + 7) & ~7;
            inv_sqrt[node] = rsqrtf((float)(c + 1));
        }
    }
}

// ---------------- scan (rowcnt -> rowstart, exclusive) ----------------
__global__ void k_scanA(const int* __restrict__ in, int* __restrict__ out,
                        int* __restrict__ bsums) {
    __shared__ int s[1024];
    int tid = threadIdx.x;
    int gid = blockIdx.x * 1024 + tid;
    int v = in[gid];
    s[tid] = v;
    __syncthreads();
    for (int off = 1; off < 1024; off <<= 1) {
        int a = (tid >= off) ? s[tid - off] : 0;
        int cur = s[tid];
        __syncthreads();
        s[tid] = cur + a;
        __syncthreads();
    }
    out[gid] = s[tid] - v;
    if (tid == 1023) bsums[blockIdx.x] = s[tid];
}

__global__ void k_scanB(int* __restrict__ bsums) {
    __shared__ int s[256];
    int tid = threadIdx.x;
    int v = (tid < SCAN_BLKS) ? bsums[tid] : 0;
    s[tid] = v;
    __syncthreads();
    for (int off = 1; off < 256; off <<= 1) {
        int a = (tid >= off) ? s[tid - off] : 0;
        int cur = s[tid];
        __syncthreads();
        s[tid] = cur + a;
        __syncthreads();
    }
    if (tid < SCAN_BLKS) bsums[tid] = s[tid] - v;
}

__global__ void k_scanC(int* __restrict__ out, const int* __restrict__ bsums) {
    int gid = blockIdx.x * 1024 + threadIdx.x;
    out[gid] += bsums[blockIdx.x];
}

// ---------------- pass 3: bucket -> padded CSR esrc ----------------
// After scattering real edges, fill pad slots [cursor, rowstart[n+1]) with NN
// (dummy node whose hws row is zero).
__global__ void k_p3_scatter(const int* __restrict__ bcursor, const int* __restrict__ ebuf,
                             const int* __restrict__ rowstart, int* __restrict__ esrc) {
    __shared__ int lcur[BWID];
    int b = blockIdx.x;
    int tid = threadIdx.x;
    int node0 = b * BWID;
    for (int i = tid; i < BWID; i += 256) lcur[i] = rowstart[node0 + i];
    __syncthreads();
    int size = bcursor[b];
    if (size > BCAP) size = BCAP;
    const int* eb = ebuf + b * BCAP;
    for (int k = tid; k < size; k += 256) {
        int v = eb[k];
        int local = v >> 18;
        int pos = atomicAdd(&lcur[local], 1);
        esrc[pos] = v & 0x3FFFF;
    }
    __syncthreads();
    for (int i = tid; i < BWID; i += 256) {
        int node = node0 + i;
        if (node < NN) {
            int end = rowstart[node + 1];
            for (int p = lcur[i]; p < end; p++) esrc[p] = NN;
        }
    }
}

// ---------------- dense matmul: hws[n,32] = (X[n,K] @ W[K,32]) * inv_sqrt[n] ----------------
// Micro-tiled 4 rows x 4 channels per thread; W broadcast from LDS. (proven form)
template <int K>
__global__ void __launch_bounds__(128, 5) k_mm(const float* __restrict__ X,
                                               const float* __restrict__ W,
                                               const float* __restrict__ inv_sqrt,
                                               float* __restrict__ Y) {
    __shared__ float4 sW[K * 8];   // sW[k*8+q] = W[k][4q..4q+3]
    int tid = threadIdx.x;
    for (int i = tid; i < K * 8; i += 128) sW[i] = ((const float4*)W)[i];
    __syncthreads();
    int g = tid >> 3;              // row-group (0..15)
    int q = tid & 7;               // channel quad (c = 4q..4q+3)
    int r0 = blockIdx.x * 64 + g * 4;
    if (r0 >= NN) return;          // NN % 4 == 0, whole group valid or not
    const float4* __restrict__ xp0 = (const float4*)(X + (size_t)(r0 + 0) * K);
    const float4* __restrict__ xp1 = (const float4*)(X + (size_t)(r0 + 1) * K);
    const float4* __restrict__ xp2 = (const float4*)(X + (size_t)(r0 + 2) * K);
    const float4* __restrict__ xp3 = (const float4*)(X + (size_t)(r0 + 3) * K);
    float4 a0 = make_float4(0.f, 0.f, 0.f, 0.f);
    float4 a1 = make_float4(0.f, 0.f, 0.f, 0.f);
    float4 a2 = make_float4(0.f, 0.f, 0.f, 0.f);
    float4 a3 = make_float4(0.f, 0.f, 0.f, 0.f);
#pragma unroll 2
    for (int k4 = 0; k4 < K / 4; k4++) {
        float4 x0 = xp0[k4];
        float4 x1 = xp1[k4];
        float4 x2 = xp2[k4];
        float4 x3 = xp3[k4];
        const float4* wk = &sW[k4 * 32 + q];
#pragma unroll
        for (int kk = 0; kk < 4; kk++) {
            float4 w = wk[kk * 8];
            float s0 = (kk == 0) ? x0.x : (kk == 1) ? x0.y : (kk == 2) ? x0.z : x0.w;
            float s1 = (kk == 0) ? x1.x : (kk == 1) ? x1.y : (kk == 2) ? x1.z : x1.w;
            float s2 = (kk == 0) ? x2.x : (kk == 1) ? x2.y : (kk == 2) ? x2.z : x2.w;
            float s3 = (kk == 0) ? x3.x : (kk == 1) ? x3.y : (kk == 2) ? x3.z : x3.w;
            a0.x = fmaf(s0, w.x, a0.x); a0.y = fmaf(s0, w.y, a0.y);
            a0.z = fmaf(s0, w.z, a0.z); a0.w = fmaf(s0, w.w, a0.w);
            a1.x = fmaf(s1, w.x, a1.x); a1.y = fmaf(s1, w.y, a1.y);
            a1.z = fmaf(s1, w.z, a1.z); a1.w = fmaf(s1, w.w, a1.w);
            a2.x = fmaf(s2, w.x, a2.x); a2.y = fmaf(s2, w.y, a2.y);
            a2.z = fmaf(s2, w.z, a2.z); a2.w = fmaf(s2, w.w, a2.w);
            a3.x = fmaf(s3, w.x, a3.x); a3.y = fmaf(s3, w.y, a3.y);
            a3.z = fmaf(s3, w.z, a3.z); a3.w = fmaf(s3, w.w, a3.w);
        }
    }
    float s0 = inv_sqrt[r0 + 0];
    float s1 = inv_sqrt[r0 + 1];
    float s2 = inv_sqrt[r0 + 2];
    float s3 = inv_sqrt[r0 + 3];
    a0.x *= s0; a0.y *= s0; a0.z *= s0; a0.w *= s0;
    a1.x *= s1; a1.y *= s1; a1.z *= s1; a1.w *= s1;
    a2.x *= s2; a2.y *= s2; a2.z *= s2; a2.w *= s2;
    a3.x *= s3; a3.y *= s3; a3.z *= s3; a3.w *= s3;
    ((float4*)(Y + (size_t)(r0 + 0) * 32))[q] = a0;
    ((float4*)(Y + (size_t)(r0 + 1) * 32))[q] = a1;
    ((float4*)(Y + (size_t)(r0 + 2) * 32))[q] = a2;
    ((float4*)(Y + (size_t)(r0 + 3) * 32))[q] = a3;
}

// ---------------- gather-aggregate, padded CSR: conditional-free 8-wide ----------------
// Rows are padded to x8 with dummy index NN (hws row NN = 0), and every
// rowstart is a multiple of 8 -> the 8 index loads collapse to two aligned
// int4 loads; no cmp/cndmask anywhere in the hot loop.
__global__ void k_aggr(const int* __restrict__ rowstart, const int* __restrict__ esrc,
                       const float* __restrict__ hws, const float* __restrict__ inv_sqrt,
                       const float* __restrict__ b, float* __restrict__ xout) {
    int t = blockIdx.x * 256 + threadIdx.x;
    int n = t >> 5, c = t & 31;
    if (n >= NN) return;
    int e0 = rowstart[n], e1 = rowstart[n + 1];
    float a[8];
    a[0] = hws[(size_t)n * 32 + c];
#pragma unroll
    for (int k = 1; k < 8; k++) a[k] = 0.0f;
    for (int e = e0; e < e1; e += 8) {
        int4 sA = *(const int4*)(esrc + e);
        int4 sB = *(const int4*)(esrc + e + 4);
        float v0 = hws[(size_t)sA.x * 32 + c];
        float v1 = hws[(size_t)sA.y * 32 + c];
        float v2 = hws[(size_t)sA.z * 32 + c];
        float v3 = hws[(size_t)sA.w * 32 + c];
        float v4 = hws[(size_t)sB.x * 32 + c];
        float v5 = hws[(size_t)sB.y * 32 + c];
        float v6 = hws[(size_t)sB.z * 32 + c];
        float v7 = hws[(size_t)sB.w * 32 + c];
        a[0] += v0; a[1] += v1; a[2] += v2; a[3] += v3;
        a[4] += v4; a[5] += v5; a[6] += v6; a[7] += v7;
    }
    float acc = ((a[0] + a[1]) + (a[2] + a[3])) + ((a[4] + a[5]) + (a[6] + a[7]));
    xout[t] = tanhf(fmaf(acc, inv_sqrt[n], b[c]));
}

// layer 4: hws4[n] = (x3[n,:] . W4) * inv_sqrt[n]; also zeroes the pad slot.
__global__ void k_mm4(const float* __restrict__ x3, const float* __restrict__ W4,
                      const float* __restrict__ inv_sqrt, float* __restrict__ hws4) {
    int n = blockIdx.x * 256 + threadIdx.x;
    if (n >= NN) return;
    if (n == 0) hws4[NN] = 0.0f;   // pad index target for k_aggr1
    const float4* xr = (const float4*)(x3 + (size_t)n * 32);
    float acc = 0.0f;
#pragma unroll
    for (int q = 0; q < 8; q++) {
        float4 v = xr[q];
        acc = fmaf(v.x, W4[q * 4 + 0], acc);
        acc = fmaf(v.y, W4[q * 4 + 1], acc);
        acc = fmaf(v.z, W4[q * 4 + 2], acc);
        acc = fmaf(v.w, W4[q * 4 + 3], acc);
    }
    hws4[n] = acc * inv_sqrt[n];
}

// layer-4 aggregation (1 channel), padded CSR: conditional-free
__global__ void k_aggr1(const int* __restrict__ rowstart, const int* __restrict__ esrc,
                        const float* __restrict__ hws4, const float* __restrict__ inv_sqrt,
                        const float* __restrict__ b4, float* __restrict__ x4) {
    int n = blockIdx.x * 256 + threadIdx.x;
    if (n >= NN) return;
    int e0 = rowstart[n], e1 = rowstart[n + 1];
    float a[8];
    a[0] = hws4[n];
#pragma unroll
    for (int k = 1; k < 8; k++) a[k] = 0.0f;
    for (int e = e0; e < e1; e += 8) {
        int4 sA = *(const int4*)(esrc + e);
        int4 sB = *(const int4*)(esrc + e + 4);
        a[0] += hws4[sA.x]; a[1] += hws4[sA.y];
        a[2] += hws4[sA.z]; a[3] += hws4[sA.w];
        a[4] += hws4[sB.x]; a[5] += hws4[sB.y];
        a[6] += hws4[sB.z]; a[7] += hws4[sB.w];
    }
    float acc = ((a[0] + a[1]) + (a[2] + a[3])) + ((a[4] + a[5]) + (a[6] + a[7]));
    x4[n] = tanhf(fmaf(acc, inv_sqrt[n], b4[0]));
}

// ---------------- graph boundaries from sorted batch (no atomics) ----------------
// starts[g] = first node index with batch[n] >= g; starts[NG] = NN
__global__ void k_gbounds(const int* __restrict__ batch, int* __restrict__ starts) {
    int n = blockIdx.x * 256 + threadIdx.x;
    if (n >= NN) return;
    int bn = batch[n];
    int bp = (n == 0) ? -1 : batch[n - 1];
    for (int g = bp + 1; g <= bn; g++) starts[g] = n;
    if (n == NN - 1)
        for (int g = bn + 1; g <= NG; g++) starts[g] = NN;
}

__global__ void k_sortpool(const int* __restrict__ starts,
                           const float* __restrict__ x1, const float* __restrict__ x2,
                           const float* __restrict__ x3, const float* __restrict__ x4,
                           float* __restrict__ pooled) {
    __shared__ float keys[1024];
    __shared__ int sel[KSEL];
    int g = blockIdx.x;
    int tid = threadIdx.x;
    int start = starts[g];
    int cnt = starts[g + 1] - start;
    if (cnt > 1024) cnt = 1024;
    for (int i = tid; i < cnt; i += 256) keys[i] = x4[start + i];
    __syncthreads();
    for (int i = tid; i < cnt; i += 256) {
        float ki = keys[i];
        int rank = 0;
        for (int j = 0; j < cnt; j++) {
            float kj = keys[j];
            rank += (kj > ki) || (kj == ki && j < i);  // stable desc, matches lexsort
        }
        if (rank < KSEL) sel[rank] = start + i;
    }
    __syncthreads();
    int selcnt = cnt < KSEL ? cnt : KSEL;
    for (int t = tid; t < KSEL * CCAT; t += 256) {
        int r = t / CCAT, ch = t - r * CCAT;
        float v = 0.0f;
        if (r < selcnt) {
            int node = sel[r];
            if (ch < 32)      v = x1[(size_t)node * 32 + ch];
            else if (ch < 64) v = x2[(size_t)node * 32 + ch - 32];
            else if (ch < 96) v = x3[(size_t)node * 32 + ch - 64];
            else              v = x4[node];
        }
        pooled[g * (KSEL * CCAT) + t] = v;
    }
}

// ---------------- CNN + MLP head, one block per graph ----------------
__global__ void k_head(const float* __restrict__ pooled,
                       const float* __restrict__ w5, const float* __restrict__ b5,
                       const float* __restrict__ w6, const float* __restrict__ b6,
                       const float* __restrict__ fw1, const float* __restrict__ fb1,
                       const float* __restrict__ fw2, const float* __restrict__ fb2,
                       float* __restrict__ out) {
    __shared__ float sP[KSEL * CCAT];
    __shared__ float s5[16 * 30];
    __shared__ float smp[16 * 15];
    __shared__ float sz[352];
    __shared__ float sh[128];
    __shared__ float sl[10];
    int g = blockIdx.x;
    int tid = threadIdx.x;
    for (int i = tid; i < KSEL * CCAT; i += 256) sP[i] = pooled[g * (KSEL * CCAT) + i];
    __syncthreads();
    for (int t = tid; t < 16 * 30; t += 256) {
        int c = t / 30, j = t - c * 30;
        float acc = b5[c];
        for (int i = 0; i < CCAT; i++) acc = fmaf(sP[j * CCAT + i], w5[c * CCAT + i], acc);
        s5[c * 30 + j] = fmaxf(acc, 0.0f);
    }
    __syncthreads();
    for (int t = tid; t < 16 * 15; t += 256) {
        int c = t / 15, j = t - c * 15;
        smp[t] = fmaxf(s5[c * 30 + 2 * j], s5[c * 30 + 2 * j + 1]);
    }
    __syncthreads();
    for (int t = tid; t < 32 * 11; t += 256) {
        int c = t / 11, j = t - c * 11;
        float acc = b6[c];
        for (int ci = 0; ci < 16; ci++) {
#pragma unroll
            for (int k = 0; k < 5; k++)
                acc = fmaf(smp[ci * 15 + j + k], w6[(c * 16 + ci) * 5 + k], acc);
        }
        sz[t] = fmaxf(acc, 0.0f);
    }
    __syncthreads();
    if (tid < 128) {
        float acc = fb1[tid];
        for (int i = 0; i < 352; i++) acc = fmaf(sz[i], fw1[i * 128 + tid], acc);
        sh[tid] = fmaxf(acc, 0.0f);
    }
    __syncthreads();
    if (tid < 10) {
        float acc = fb2[tid];
        for (int i = 0; i < 128; i++) acc = fmaf(sh[i], fw2[i * 10 + tid], acc);
        sl[tid] = acc;
    }
    __syncthreads();
    if (tid < 10) {
        float m = -1e30f;
        for (int i = 0; i < 10; i++) m = fmaxf(m, sl[i]);
        float ssum = 0.0f;
        for (int i = 0; i < 10; i++) ssum += expf(sl[i] - m);
        out[g * 10 + tid] = sl[tid] - m - logf(ssum);
    }
}

extern "C" void kernel_launch(void* const* d_in, const int* in_sizes, int n_in,
                              void* d_out, int out_size, void* d_ws, size_t ws_size,
                              hipStream_t stream) {
    const float* x   = (const float*)d_in[0];
    const int*   ei  = (const int*)d_in[1];
    const int*   bat = (const int*)d_in[2];
    const float* W1  = (const float*)d_in[3];
    const float* b1  = (const float*)d_in[4];
    const float* W2  = (const float*)d_in[5];
    const float* b2  = (const float*)d_in[6];
    const float* W3  = (const float*)d_in[7];
    const float* b3  = (const float*)d_in[8];
    const float* W4  = (const float*)d_in[9];
    const float* b4  = (const float*)d_in[10];
    const float* w5  = (const float*)d_in[11];
    const float* b5  = (const float*)d_in[12];
    const float* w6  = (const float*)d_in[13];
    const float* b6  = (const float*)d_in[14];
    const float* fw1 = (const float*)d_in[15];
    const float* fb1 = (const float*)d_in[16];
    const float* fw2 = (const float*)d_in[17];
    const float* fb2 = (const float*)d_in[18];
    float* out = (float*)d_out;

    float* ws = (float*)d_ws;
    float* inv_sqrt = ws;                             // NN
    float* hws      = inv_sqrt + NN;                  // (NN+1)*32 (row NN = zero pad; first NN floats double as hws4)
    float* x1       = hws + (size_t)(NN + 1) * 32;    // NN*32
    float* x2       = x1 + (size_t)NN * 32;           // NN*32
    float* x3       = x2 + (size_t)NN * 32;           // NN*32
    float* x4       = x3 + (size_t)NN * 32;           // NN
    float* pooled   = x4 + NN;                        // NG*KSEL*CCAT
    int* rowcnt     = (int*)(pooled + NG * KSEL * CCAT);  // NPAD
    int* rowstart   = rowcnt + NPAD;                  // NPAD
    int* esrc       = rowstart + NPAD;                // EPADCAP
    int* bcursor    = esrc + EPADCAP;                 // NB (pad to 512)
    int* bsums      = bcursor + 512;                  // 256
    int* gstarts    = bsums + 256;                    // NG+1 (pad to 1024)
    int* ebuf       = (int*)x3;                       // NB*BCAP ints (16 MB), dead before x3 written

    const int TB = 256;
    int gN  = (NN + TB - 1) / TB;
    int gNC = (NN * 32 + TB - 1) / TB;
    int gMM = (NN + 63) / 64;      // 64 rows per 128-thread block in k_mm

    // ---- CSR build via bucketed partition ----
    hipMemsetAsync(bcursor, 0, 512 * sizeof(int), stream);
    hipMemsetAsync(rowcnt, 0, NPAD * sizeof(int), stream);
    hipMemsetAsync(hws + (size_t)NN * 32, 0, 32 * sizeof(float), stream);  // zero pad row
    k_p1_partition<<<P1_BLKS, TB, 0, stream>>>(ei, bcursor, ebuf);
    k_p2_count<<<NB, TB, 0, stream>>>(bcursor, ebuf, rowcnt, inv_sqrt);
    k_scanA<<<SCAN_BLKS, 1024, 0, stream>>>(rowcnt, rowstart, bsums);
    k_scanB<<<1, 256, 0, stream>>>(bsums);
    k_scanC<<<SCAN_BLKS, 1024, 0, stream>>>(rowstart, bsums);
    k_p3_scatter<<<NB, TB, 0, stream>>>(bcursor, ebuf, rowstart, esrc);

    // ---- graph boundaries (sorted batch -> no atomics) ----
    k_gbounds<<<gN, TB, 0, stream>>>(bat, gstarts);

    // ---- GCN layers ----
    k_mm<128><<<gMM, 128, 0, stream>>>(x, W1, inv_sqrt, hws);
    k_aggr<<<gNC, TB, 0, stream>>>(rowstart, esrc, hws, inv_sqrt, b1, x1);
    k_mm<32><<<gMM, 128, 0, stream>>>(x1, W2, inv_sqrt, hws);
    k_aggr<<<gNC, TB, 0, stream>>>(rowstart, esrc, hws, inv_sqrt, b2, x2);
    k_mm<32><<<gMM, 128, 0, stream>>>(x2, W3, inv_sqrt, hws);
    k_aggr<<<gNC, TB, 0, stream>>>(rowstart, esrc, hws, inv_sqrt, b3, x3);
    k_mm4<<<gN, TB, 0, stream>>>(x3, W4, inv_sqrt, hws);
    k_aggr1<<<gN, TB, 0, stream>>>(rowstart, esrc, hws, inv_sqrt, b4, x4);

    // ---- sort-pool + head ----
    k_sortpool<<<NG, TB, 0, stream>>>(gstarts, x1, x2, x3, x4, pooled);
    k_head<<<NG, TB, 0, stream>>>(pooled, w5, b5, w6, b6, fw1, fb1, fw2, fb2, out);
}

// Round 7
// 585.554 us; speedup vs baseline: 2.2769x; 1.0243x over previous
//
#include <hip/hip_runtime.h>
#include <math.h>

#define NN 200000
#define NE 3200000
#define NF 128
#define NG 1000
#define KSEL 30
#define CCAT 97
#define NPAD 200704      // 196 * 1024, padded node count for the scan
#define SCAN_BLKS 196
#define EPADCAP (NE + 8 * NN)     // padded-CSR esrc capacity

#define BWID 512                  // nodes per bucket (dst >> 9)
#define NB 391                    // ceil(NN / BWID)
#define BCAP 10240                // per-bucket edge capacity (mean 8184, sigma ~90)
#define P1_CHUNK 8192             // edges per block in partition pass
#define P1_BLKS 391               // ceil(NE / P1_CHUNK)

// ---------------- pass 1: partition edges into dst-buckets ----------------
__global__ void k_p1_partition(const int* __restrict__ ei, int* __restrict__ bcursor,
                               int* __restrict__ ebuf) {
    __shared__ int lhist[NB];
    __shared__ int lbase[NB];
    int tid = threadIdx.x;
    int base = blockIdx.x * P1_CHUNK;
    for (int b = tid; b < NB; b += 256) lhist[b] = 0;
    __syncthreads();
    for (int it = 0; it < P1_CHUNK / 256; it++) {
        int e = base + it * 256 + tid;
        if (e < NE) {
            int s = ei[e], d = ei[NE + e];
            if (s != d) atomicAdd(&lhist[d >> 9], 1);
        }
    }
    __syncthreads();
    for (int b = tid; b < NB; b += 256) {
        int cnt = lhist[b];
        lbase[b] = cnt ? atomicAdd(&bcursor[b], cnt) : 0;
        lhist[b] = 0;
    }
    __syncthreads();
    for (int it = 0; it < P1_CHUNK / 256; it++) {
        int e = base + it * 256 + tid;
        if (e < NE) {
            int s = ei[e], d = ei[NE + e];
            if (s != d) {
                int b = d >> 9;
                int r = atomicAdd(&lhist[b], 1);
                int pos = lbase[b] + r;
                if (pos >= BCAP) pos = BCAP - 1;  // defensive (cannot happen)
                ebuf[b * BCAP + pos] = s | ((d & 511) << 18);
            }
        }
    }
}

// ---------------- pass 2: per-bucket node counts + inv_sqrt ----------------
// rowcnt gets the count PADDED to a multiple of 8 (for conditional-free aggr);
// inv_sqrt uses the real count.
__global__ void k_p2_count(const int* __restrict__ bcursor, const int* __restrict__ ebuf,
                           int* __restrict__ rowcnt, float* __restrict__ inv_sqrt) {
    __shared__ int lcnt[BWID];
    int b = blockIdx.x;
    int tid = threadIdx.x;
    for (int i = tid; i < BWID; i += 256) lcnt[i] = 0;
    __syncthreads();
    int size = bcursor[b];
    if (size > BCAP) size = BCAP;
    const int* eb = ebuf + b * BCAP;
    for (int k = tid; k < size; k += 256) atomicAdd(&lcnt[eb[k] >> 18], 1);
    __syncthreads();
    int node0 = b * BWID;
    for (int i = tid; i < BWID; i += 256) {
        int node = node0 + i;
        if (node < NN) {
            int c = lcnt[i];
            rowcnt[node] = (c + 7) & ~7;
            inv_sqrt[node] = rsqrtf((float)(c + 1));
        }
    }
}

// ---------------- scan (rowcnt -> rowstart, exclusive) ----------------
__global__ void k_scanA(const int* __restrict__ in, int* __restrict__ out,
                        int* __restrict__ bsums) {
    __shared__ int s[1024];
    int tid = threadIdx.x;
    int gid = blockIdx.x * 1024 + tid;
    int v = in[gid];
    s[tid] = v;
    __syncthreads();
    for (int off = 1; off < 1024; off <<= 1) {
        int a = (tid >= off) ? s[tid - off] : 0;
        int cur = s[tid];
        __syncthreads();
        s[tid] = cur + a;
        __syncthreads();
    }
    out[gid] = s[tid] - v;
    if (tid == 1023) bsums[blockIdx.x] = s[tid];
}

__global__ void k_scanB(int* __restrict__ bsums) {
    __shared__ int s[256];
    int tid = threadIdx.x;
    int v = (tid < SCAN_BLKS) ? bsums[tid] : 0;
    s[tid] = v;
    __syncthreads();
    for (int off = 1; off < 256; off <<= 1) {
        int a = (tid >= off) ? s[tid - off] : 0;
        int cur = s[tid];
        __syncthreads();
        s[tid] = cur + a;
        __syncthreads();
    }
    if (tid < SCAN_BLKS) bsums[tid] = s[tid] - v;
}

__global__ void k_scanC(int* __restrict__ out, const int* __restrict__ bsums) {
    int gid = blockIdx.x * 1024 + threadIdx.x;
    out[gid] += bsums[blockIdx.x];
}

// ---------------- pass 3: bucket -> padded CSR esrc ----------------
// After scattering real edges, fill pad slots [cursor, rowstart[n+1]) with NN
// (dummy node whose hws row is zero).
__global__ void k_p3_scatter(const int* __restrict__ bcursor, const int* __restrict__ ebuf,
                             const int* __restrict__ rowstart, int* __restrict__ esrc) {
    __shared__ int lcur[BWID];
    int b = blockIdx.x;
    int tid = threadIdx.x;
    int node0 = b * BWID;
    for (int i = tid; i < BWID; i += 256) lcur[i] = rowstart[node0 + i];
    __syncthreads();
    int size = bcursor[b];
    if (size > BCAP) size = BCAP;
    const int* eb = ebuf + b * BCAP;
    for (int k = tid; k < size; k += 256) {
        int v = eb[k];
        int local = v >> 18;
        int pos = atomicAdd(&lcur[local], 1);
        esrc[pos] = v & 0x3FFFF;
    }
    __syncthreads();
    for (int i = tid; i < BWID; i += 256) {
        int node = node0 + i;
        if (node < NN) {
            int end = rowstart[node + 1];
            for (int p = lcur[i]; p < end; p++) esrc[p] = NN;
        }
    }
}

// ---------------- dense matmul: hws[n,32] = (X[n,K] @ W[K,32]) * inv_sqrt[n] ----------------
// LDS-staged X tile: the block's 64-row X slab is CONTIGUOUS in global memory,
// staged once (coalesced streaming, deep natural pipelining), then the compute
// loop reads only LDS -> no global latency inside the FMA loop (compiler
// schedules fine-grained lgkmcnt). sX rows padded +1 float4: 2-row group
// stride = 264 words = 8 mod 32 -> 2-way bank aliasing (free).
// 256 threads, 64 rows/block (3125 blocks exactly), 2 rows x 4 ch per thread.
template <int K>
__global__ void __launch_bounds__(256, 3) k_mm(const float* __restrict__ X,
                                               const float* __restrict__ W,
                                               const float* __restrict__ inv_sqrt,
                                               float* __restrict__ Y) {
    constexpr int K4 = K / 4;          // float4 per row
    constexpr int RS = K4 + 1;         // padded row stride in float4
    __shared__ float4 sW[K * 8];       // sW[k*8+q] = W[k][4q..4q+3]
    __shared__ float4 sX[64 * RS];
    int tid = threadIdx.x;
    for (int i = tid; i < K * 8; i += 256) sW[i] = ((const float4*)W)[i];
    const float4* __restrict__ Xg = (const float4*)(X + (size_t)blockIdx.x * 64 * K);
    for (int i = tid; i < 64 * K4; i += 256) {
        int row = i / K4;
        int col = i & (K4 - 1);
        sX[row * RS + col] = Xg[i];
    }
    __syncthreads();
    int g = tid >> 3;                  // 0..31, 2 rows each
    int q = tid & 7;                   // channel quad (c = 4q..4q+3)
    int r0 = blockIdx.x * 64 + g * 2;  // grid is exact: no bounds check needed
    const float4* __restrict__ xr0 = &sX[(size_t)(g * 2 + 0) * RS];
    const float4* __restrict__ xr1 = &sX[(size_t)(g * 2 + 1) * RS];
    float4 a0 = make_float4(0.f, 0.f, 0.f, 0.f);
    float4 a1 = make_float4(0.f, 0.f, 0.f, 0.f);
#pragma unroll 4
    for (int k4 = 0; k4 < K4; k4++) {
        float4 x0 = xr0[k4];
        float4 x1 = xr1[k4];
        const float4* wk = &sW[k4 * 32 + q];
#pragma unroll
        for (int kk = 0; kk < 4; kk++) {
            float4 w = wk[kk * 8];
            float s0 = (kk == 0) ? x0.x : (kk == 1) ? x0.y : (kk == 2) ? x0.z : x0.w;
            float s1 = (kk == 0) ? x1.x : (kk == 1) ? x1.y : (kk == 2) ? x1.z : x1.w;
            a0.x = fmaf(s0, w.x, a0.x); a0.y = fmaf(s0, w.y, a0.y);
            a0.z = fmaf(s0, w.z, a0.z); a0.w = fmaf(s0, w.w, a0.w);
            a1.x = fmaf(s1, w.x, a1.x); a1.y = fmaf(s1, w.y, a1.y);
            a1.z = fmaf(s1, w.z, a1.z); a1.w = fmaf(s1, w.w, a1.w);
        }
    }
    float s0 = inv_sqrt[r0 + 0];
    float s1 = inv_sqrt[r0 + 1];
    a0.x *= s0; a0.y *= s0; a0.z *= s0; a0.w *= s0;
    a1.x *= s1; a1.y *= s1; a1.z *= s1; a1.w *= s1;
    ((float4*)(Y + (size_t)(r0 + 0) * 32))[q] = a0;
    ((float4*)(Y + (size_t)(r0 + 1) * 32))[q] = a1;
}

// ---------------- gather-aggregate, padded CSR: conditional-free 8-wide ----------------
__global__ void k_aggr(const int* __restrict__ rowstart, const int* __restrict__ esrc,
                       const float* __restrict__ hws, const float* __restrict__ inv_sqrt,
                       const float* __restrict__ b, float* __restrict__ xout) {
    int t = blockIdx.x * 256 + threadIdx.x;
    int n = t >> 5, c = t & 31;
    if (n >= NN) return;
    int e0 = rowstart[n], e1 = rowstart[n + 1];
    float a[8];
    a[0] = hws[(size_t)n * 32 + c];
#pragma unroll
    for (int k = 1; k < 8; k++) a[k] = 0.0f;
    for (int e = e0; e < e1; e += 8) {
        int4 sA = *(const int4*)(esrc + e);
        int4 sB = *(const int4*)(esrc + e + 4);
        float v0 = hws[(size_t)sA.x * 32 + c];
        float v1 = hws[(size_t)sA.y * 32 + c];
        float v2 = hws[(size_t)sA.z * 32 + c];
        float v3 = hws[(size_t)sA.w * 32 + c];
        float v4 = hws[(size_t)sB.x * 32 + c];
        float v5 = hws[(size_t)sB.y * 32 + c];
        float v6 = hws[(size_t)sB.z * 32 + c];
        float v7 = hws[(size_t)sB.w * 32 + c];
        a[0] += v0; a[1] += v1; a[2] += v2; a[3] += v3;
        a[4] += v4; a[5] += v5; a[6] += v6; a[7] += v7;
    }
    float acc = ((a[0] + a[1]) + (a[2] + a[3])) + ((a[4] + a[5]) + (a[6] + a[7]));
    xout[t] = tanhf(fmaf(acc, inv_sqrt[n], b[c]));
}

// layer 4: hws4[n] = (x3[n,:] . W4) * inv_sqrt[n]; also zeroes the pad slot.
__global__ void k_mm4(const float* __restrict__ x3, const float* __restrict__ W4,
                      const float* __restrict__ inv_sqrt, float* __restrict__ hws4) {
    int n = blockIdx.x * 256 + threadIdx.x;
    if (n >= NN) return;
    if (n == 0) hws4[NN] = 0.0f;   // pad index target for k_aggr1
    const float4* xr = (const float4*)(x3 + (size_t)n * 32);
    float acc = 0.0f;
#pragma unroll
    for (int q = 0; q < 8; q++) {
        float4 v = xr[q];
        acc = fmaf(v.x, W4[q * 4 + 0], acc);
        acc = fmaf(v.y, W4[q * 4 + 1], acc);
        acc = fmaf(v.z, W4[q * 4 + 2], acc);
        acc = fmaf(v.w, W4[q * 4 + 3], acc);
    }
    hws4[n] = acc * inv_sqrt[n];
}

// layer-4 aggregation (1 channel), padded CSR: conditional-free
__global__ void k_aggr1(const int* __restrict__ rowstart, const int* __restrict__ esrc,
                        const float* __restrict__ hws4, const float* __restrict__ inv_sqrt,
                        const float* __restrict__ b4, float* __restrict__ x4) {
    int n = blockIdx.x * 256 + threadIdx.x;
    if (n >= NN) return;
    int e0 = rowstart[n], e1 = rowstart[n + 1];
    float a[8];
    a[0] = hws4[n];
#pragma unroll
    for (int k = 1; k < 8; k++) a[k] = 0.0f;
    for (int e = e0; e < e1; e += 8) {
        int4 sA = *(const int4*)(esrc + e);
        int4 sB = *(const int4*)(esrc + e + 4);
        a[0] += hws4[sA.x]; a[1] += hws4[sA.y];
        a[2] += hws4[sA.z]; a[3] += hws4[sA.w];
        a[4] += hws4[sB.x]; a[5] += hws4[sB.y];
        a[6] += hws4[sB.z]; a[7] += hws4[sB.w];
    }
    float acc = ((a[0] + a[1]) + (a[2] + a[3])) + ((a[4] + a[5]) + (a[6] + a[7]));
    x4[n] = tanhf(fmaf(acc, inv_sqrt[n], b4[0]));
}

// ---------------- graph boundaries from sorted batch (no atomics) ----------------
// starts[g] = first node index with batch[n] >= g; starts[NG] = NN
__global__ void k_gbounds(const int* __restrict__ batch, int* __restrict__ starts) {
    int n = blockIdx.x * 256 + threadIdx.x;
    if (n >= NN) return;
    int bn = batch[n];
    int bp = (n == 0) ? -1 : batch[n - 1];
    for (int g = bp + 1; g <= bn; g++) starts[g] = n;
    if (n == NN - 1)
        for (int g = bn + 1; g <= NG; g++) starts[g] = NN;
}

__global__ void k_sortpool(const int* __restrict__ starts,
                           const float* __restrict__ x1, const float* __restrict__ x2,
                           const float* __restrict__ x3, const float* __restrict__ x4,
                           float* __restrict__ pooled) {
    __shared__ float keys[1024];
    __shared__ int sel[KSEL];
    int g = blockIdx.x;
    int tid = threadIdx.x;
    int start = starts[g];
    int cnt = starts[g + 1] - start;
    if (cnt > 1024) cnt = 1024;
    for (int i = tid; i < cnt; i += 256) keys[i] = x4[start + i];
    __syncthreads();
    for (int i = tid; i < cnt; i += 256) {
        float ki = keys[i];
        int rank = 0;
        for (int j = 0; j < cnt; j++) {
            float kj = keys[j];
            rank += (kj > ki) || (kj == ki && j < i);  // stable desc, matches lexsort
        }
        if (rank < KSEL) sel[rank] = start + i;
    }
    __syncthreads();
    int selcnt = cnt < KSEL ? cnt : KSEL;
    for (int t = tid; t < KSEL * CCAT; t += 256) {
        int r = t / CCAT, ch = t - r * CCAT;
        float v = 0.0f;
        if (r < selcnt) {
            int node = sel[r];
            if (ch < 32)      v = x1[(size_t)node * 32 + ch];
            else if (ch < 64) v = x2[(size_t)node * 32 + ch - 32];
            else if (ch < 96) v = x3[(size_t)node * 32 + ch - 64];
            else              v = x4[node];
        }
        pooled[g * (KSEL * CCAT) + t] = v;
    }
}

// ---------------- CNN + MLP head, one block per graph ----------------
__global__ void k_head(const float* __restrict__ pooled,
                       const float* __restrict__ w5, const float* __restrict__ b5,
                       const float* __restrict__ w6, const float* __restrict__ b6,
                       const float* __restrict__ fw1, const float* __restrict__ fb1,
                       const float* __restrict__ fw2, const float* __restrict__ fb2,
                       float* __restrict__ out) {
    __shared__ float sP[KSEL * CCAT];
    __shared__ float s5[16 * 30];
    __shared__ float smp[16 * 15];
    __shared__ float sz[352];
    __shared__ float sh[128];
    __shared__ float sl[10];
    int g = blockIdx.x;
    int tid = threadIdx.x;
    for (int i = tid; i < KSEL * CCAT; i += 256) sP[i] = pooled[g * (KSEL * CCAT) + i];
    __syncthreads();
    for (int t = tid; t < 16 * 30; t += 256) {
        int c = t / 30, j = t - c * 30;
        float acc = b5[c];
        for (int i = 0; i < CCAT; i++) acc = fmaf(sP[j * CCAT + i], w5[c * CCAT + i], acc);
        s5[c * 30 + j] = fmaxf(acc, 0.0f);
    }
    __syncthreads();
    for (int t = tid; t < 16 * 15; t += 256) {
        int c = t / 15, j = t - c * 15;
        smp[t] = fmaxf(s5[c * 30 + 2 * j], s5[c * 30 + 2 * j + 1]);
    }
    __syncthreads();
    for (int t = tid; t < 32 * 11; t += 256) {
        int c = t / 11, j = t - c * 11;
        float acc = b6[c];
        for (int ci = 0; ci < 16; ci++) {
#pragma unroll
            for (int k = 0; k < 5; k++)
                acc = fmaf(smp[ci * 15 + j + k], w6[(c * 16 + ci) * 5 + k], acc);
        }
        sz[t] = fmaxf(acc, 0.0f);
    }
    __syncthreads();
    if (tid < 128) {
        float acc = fb1[tid];
        for (int i = 0; i < 352; i++) acc = fmaf(sz[i], fw1[i * 128 + tid], acc);
        sh[tid] = fmaxf(acc, 0.0f);
    }
    __syncthreads();
    if (tid < 10) {
        float acc = fb2[tid];
        for (int i = 0; i < 128; i++) acc = fmaf(sh[i], fw2[i * 10 + tid], acc);
        sl[tid] = acc;
    }
    __syncthreads();
    if (tid < 10) {
        float m = -1e30f;
        for (int i = 0; i < 10; i++) m = fmaxf(m, sl[i]);
        float ssum = 0.0f;
        for (int i = 0; i < 10; i++) ssum += expf(sl[i] - m);
        out[g * 10 + tid] = sl[tid] - m - logf(ssum);
    }
}

extern "C" void kernel_launch(void* const* d_in, const int* in_sizes, int n_in,
                              void* d_out, int out_size, void* d_ws, size_t ws_size,
                              hipStream_t stream) {
    const float* x   = (const float*)d_in[0];
    const int*   ei  = (const int*)d_in[1];
    const int*   bat = (const int*)d_in[2];
    const float* W1  = (const float*)d_in[3];
    const float* b1  = (const float*)d_in[4];
    const float* W2  = (const float*)d_in[5];
    const float* b2  = (const float*)d_in[6];
    const float* W3  = (const float*)d_in[7];
    const float* b3  = (const float*)d_in[8];
    const float* W4  = (const float*)d_in[9];
    const float* b4  = (const float*)d_in[10];
    const float* w5  = (const float*)d_in[11];
    const float* b5  = (const float*)d_in[12];
    const float* w6  = (const float*)d_in[13];
    const float* b6  = (const float*)d_in[14];
    const float* fw1 = (const float*)d_in[15];
    const float* fb1 = (const float*)d_in[16];
    const float* fw2 = (const float*)d_in[17];
    const float* fb2 = (const float*)d_in[18];
    float* out = (float*)d_out;

    float* ws = (float*)d_ws;
    float* inv_sqrt = ws;                             // NN
    float* hws      = inv_sqrt + NN;                  // (NN+1)*32 (row NN = zero pad; first NN floats double as hws4)
    float* x1       = hws + (size_t)(NN + 1) * 32;    // NN*32
    float* x2       = x1 + (size_t)NN * 32;           // NN*32
    float* x3       = x2 + (size_t)NN * 32;           // NN*32
    float* x4       = x3 + (size_t)NN * 32;           // NN
    float* pooled   = x4 + NN;                        // NG*KSEL*CCAT
    int* rowcnt     = (int*)(pooled + NG * KSEL * CCAT);  // NPAD
    int* rowstart   = rowcnt + NPAD;                  // NPAD
    int* esrc       = rowstart + NPAD;                // EPADCAP
    int* bcursor    = esrc + EPADCAP;                 // NB (pad to 512)
    int* bsums      = bcursor + 512;                  // 256
    int* gstarts    = bsums + 256;                    // NG+1 (pad to 1024)
    int* ebuf       = (int*)x3;                       // NB*BCAP ints (16 MB), dead before x3 written

    const int TB = 256;
    int gN  = (NN + TB - 1) / TB;
    int gNC = (NN * 32 + TB - 1) / TB;
    int gMM = NN / 64;             // 64 rows per 256-thread block in k_mm (exact: 3125)

    // ---- CSR build via bucketed partition ----
    hipMemsetAsync(bcursor, 0, 512 * sizeof(int), stream);
    hipMemsetAsync(rowcnt, 0, NPAD * sizeof(int), stream);
    hipMemsetAsync(hws + (size_t)NN * 32, 0, 32 * sizeof(float), stream);  // zero pad row
    k_p1_partition<<<P1_BLKS, TB, 0, stream>>>(ei, bcursor, ebuf);
    k_p2_count<<<NB, TB, 0, stream>>>(bcursor, ebuf, rowcnt, inv_sqrt);
    k_scanA<<<SCAN_BLKS, 1024, 0, stream>>>(rowcnt, rowstart, bsums);
    k_scanB<<<1, 256, 0, stream>>>(bsums);
    k_scanC<<<SCAN_BLKS, 1024, 0, stream>>>(rowstart, bsums);
    k_p3_scatter<<<NB, TB, 0, stream>>>(bcursor, ebuf, rowstart, esrc);

    // ---- graph boundaries (sorted batch -> no atomics) ----
    k_gbounds<<<gN, TB, 0, stream>>>(bat, gstarts);

    // ---- GCN layers ----
    k_mm<128><<<gMM, TB, 0, stream>>>(x, W1, inv_sqrt, hws);
    k_aggr<<<gNC, TB, 0, stream>>>(rowstart, esrc, hws, inv_sqrt, b1, x1);
    k_mm<32><<<gMM, TB, 0, stream>>>(x1, W2, inv_sqrt, hws);
    k_aggr<<<gNC, TB, 0, stream>>>(rowstart, esrc, hws, inv_sqrt, b2, x2);
    k_mm<32><<<gMM, TB, 0, stream>>>(x2, W3, inv_sqrt, hws);
    k_aggr<<<gNC, TB, 0, stream>>>(rowstart, esrc, hws, inv_sqrt, b3, x3);
    k_mm4<<<gN, TB, 0, stream>>>(x3, W4, inv_sqrt, hws);
    k_aggr1<<<gN, TB, 0, stream>>>(rowstart, esrc, hws, inv_sqrt, b4, x4);

    // ---- sort-pool + head ----
    k_sortpool<<<NG, TB, 0, stream>>>(gstarts, x1, x2, x3, x4, pooled);
    k_head<<<NG, TB, 0, stream>>>(pooled, w5, b5, w6, b6, fw1, fb1, fw2, fb2, out);
}

// Round 8
// 575.123 us; speedup vs baseline: 2.3182x; 1.0181x over previous
//
#include <hip/hip_runtime.h>
#include <math.h>

#define NN 200000
#define NE 3200000
#define NF 128
#define NG 1000
#define KSEL 30
#define CCAT 97
#define NPAD 200704      // 196 * 1024, padded node count for the scan
#define SCAN_BLKS 196
#define EPADCAP (NE + 8 * NN)     // padded-CSR esrc capacity

#define BWID 512                  // nodes per bucket (dst >> 9)
#define NB 391                    // ceil(NN / BWID)
#define BCAP 10240                // per-bucket edge capacity (mean 8184, sigma ~90)
#define P1_CHUNK 8192             // edges per block in partition pass
#define P1_BLKS 391               // ceil(NE / P1_CHUNK)

// ---------------- pass 1: partition edges into dst-buckets ----------------
__global__ void k_p1_partition(const int* __restrict__ ei, int* __restrict__ bcursor,
                               int* __restrict__ ebuf) {
    __shared__ int lhist[NB];
    __shared__ int lbase[NB];
    int tid = threadIdx.x;
    int base = blockIdx.x * P1_CHUNK;
    for (int b = tid; b < NB; b += 256) lhist[b] = 0;
    __syncthreads();
    for (int it = 0; it < P1_CHUNK / 256; it++) {
        int e = base + it * 256 + tid;
        if (e < NE) {
            int s = ei[e], d = ei[NE + e];
            if (s != d) atomicAdd(&lhist[d >> 9], 1);
        }
    }
    __syncthreads();
    for (int b = tid; b < NB; b += 256) {
        int cnt = lhist[b];
        lbase[b] = cnt ? atomicAdd(&bcursor[b], cnt) : 0;
        lhist[b] = 0;
    }
    __syncthreads();
    for (int it = 0; it < P1_CHUNK / 256; it++) {
        int e = base + it * 256 + tid;
        if (e < NE) {
            int s = ei[e], d = ei[NE + e];
            if (s != d) {
                int b = d >> 9;
                int r = atomicAdd(&lhist[b], 1);
                int pos = lbase[b] + r;
                if (pos >= BCAP) pos = BCAP - 1;  // defensive (cannot happen)
                ebuf[b * BCAP + pos] = s | ((d & 511) << 18);
            }
        }
    }
}

// ---------------- pass 2: per-bucket node counts + inv_sqrt ----------------
__global__ void k_p2_count(const int* __restrict__ bcursor, const int* __restrict__ ebuf,
                           int* __restrict__ rowcnt, float* __restrict__ inv_sqrt) {
    __shared__ int lcnt[BWID];
    int b = blockIdx.x;
    int tid = threadIdx.x;
    for (int i = tid; i < BWID; i += 256) lcnt[i] = 0;
    __syncthreads();
    int size = bcursor[b];
    if (size > BCAP) size = BCAP;
    const int* eb = ebuf + b * BCAP;
    for (int k = tid; k < size; k += 256) atomicAdd(&lcnt[eb[k] >> 18], 1);
    __syncthreads();
    int node0 = b * BWID;
    for (int i = tid; i < BWID; i += 256) {
        int node = node0 + i;
        if (node < NN) {
            int c = lcnt[i];
            rowcnt[node] = (c + 7) & ~7;
            inv_sqrt[node] = rsqrtf((float)(c + 1));
        }
    }
}

// ---------------- scan (rowcnt -> rowstart, exclusive) ----------------
__global__ void k_scanA(const int* __restrict__ in, int* __restrict__ out,
                        int* __restrict__ bsums) {
    __shared__ int s[1024];
    int tid = threadIdx.x;
    int gid = blockIdx.x * 1024 + tid;
    int v = in[gid];
    s[tid] = v;
    __syncthreads();
    for (int off = 1; off < 1024; off <<= 1) {
        int a = (tid >= off) ? s[tid - off] : 0;
        int cur = s[tid];
        __syncthreads();
        s[tid] = cur + a;
        __syncthreads();
    }
    out[gid] = s[tid] - v;
    if (tid == 1023) bsums[blockIdx.x] = s[tid];
}

__global__ void k_scanB(int* __restrict__ bsums) {
    __shared__ int s[256];
    int tid = threadIdx.x;
    int v = (tid < SCAN_BLKS) ? bsums[tid] : 0;
    s[tid] = v;
    __syncthreads();
    for (int off = 1; off < 256; off <<= 1) {
        int a = (tid >= off) ? s[tid - off] : 0;
        int cur = s[tid];
        __syncthreads();
        s[tid] = cur + a;
        __syncthreads();
    }
    if (tid < SCAN_BLKS) bsums[tid] = s[tid] - v;
}

__global__ void k_scanC(int* __restrict__ out, const int* __restrict__ bsums) {
    int gid = blockIdx.x * 1024 + threadIdx.x;
    out[gid] += bsums[blockIdx.x];
}

// ---------------- pass 3: bucket -> padded CSR esrc ----------------
__global__ void k_p3_scatter(const int* __restrict__ bcursor, const int* __restrict__ ebuf,
                             const int* __restrict__ rowstart, int* __restrict__ esrc) {
    __shared__ int lcur[BWID];
    int b = blockIdx.x;
    int tid = threadIdx.x;
    int node0 = b * BWID;
    for (int i = tid; i < BWID; i += 256) lcur[i] = rowstart[node0 + i];
    __syncthreads();
    int size = bcursor[b];
    if (size > BCAP) size = BCAP;
    const int* eb = ebuf + b * BCAP;
    for (int k = tid; k < size; k += 256) {
        int v = eb[k];
        int local = v >> 18;
        int pos = atomicAdd(&lcur[local], 1);
        esrc[pos] = v & 0x3FFFF;
    }
    __syncthreads();
    for (int i = tid; i < BWID; i += 256) {
        int node = node0 + i;
        if (node < NN) {
            int end = rowstart[node + 1];
            for (int p = lcur[i]; p < end; p++) esrc[p] = NN;
        }
    }
}

// ---------------- dense matmul (layer 1 only): hws[n,32] = (X[n,K]@W)*invs ----------------
// LDS-staged X tile (proven round-7 form).
template <int K>
__global__ void __launch_bounds__(256, 3) k_mm(const float* __restrict__ X,
                                               const float* __restrict__ W,
                                               const float* __restrict__ inv_sqrt,
                                               float* __restrict__ Y) {
    constexpr int K4 = K / 4;          // float4 per row
    constexpr int RS = K4 + 1;         // padded row stride in float4
    __shared__ float4 sW[K * 8];       // sW[k*8+q] = W[k][4q..4q+3]
    __shared__ float4 sX[64 * RS];
    int tid = threadIdx.x;
    for (int i = tid; i < K * 8; i += 256) sW[i] = ((const float4*)W)[i];
    const float4* __restrict__ Xg = (const float4*)(X + (size_t)blockIdx.x * 64 * K);
    for (int i = tid; i < 64 * K4; i += 256) {
        int row = i / K4;
        int col = i & (K4 - 1);
        sX[row * RS + col] = Xg[i];
    }
    __syncthreads();
    int g = tid >> 3;                  // 0..31, 2 rows each
    int q = tid & 7;                   // channel quad (c = 4q..4q+3)
    int r0 = blockIdx.x * 64 + g * 2;  // grid is exact: no bounds check needed
    const float4* __restrict__ xr0 = &sX[(size_t)(g * 2 + 0) * RS];
    const float4* __restrict__ xr1 = &sX[(size_t)(g * 2 + 1) * RS];
    float4 a0 = make_float4(0.f, 0.f, 0.f, 0.f);
    float4 a1 = make_float4(0.f, 0.f, 0.f, 0.f);
#pragma unroll 4
    for (int k4 = 0; k4 < K4; k4++) {
        float4 x0 = xr0[k4];
        float4 x1 = xr1[k4];
        const float4* wk = &sW[k4 * 32 + q];
#pragma unroll
        for (int kk = 0; kk < 4; kk++) {
            float4 w = wk[kk * 8];
            float s0 = (kk == 0) ? x0.x : (kk == 1) ? x0.y : (kk == 2) ? x0.z : x0.w;
            float s1 = (kk == 0) ? x1.x : (kk == 1) ? x1.y : (kk == 2) ? x1.z : x1.w;
            a0.x = fmaf(s0, w.x, a0.x); a0.y = fmaf(s0, w.y, a0.y);
            a0.z = fmaf(s0, w.z, a0.z); a0.w = fmaf(s0, w.w, a0.w);
            a1.x = fmaf(s1, w.x, a1.x); a1.y = fmaf(s1, w.y, a1.y);
            a1.z = fmaf(s1, w.z, a1.z); a1.w = fmaf(s1, w.w, a1.w);
        }
    }
    float s0 = inv_sqrt[r0 + 0];
    float s1 = inv_sqrt[r0 + 1];
    a0.x *= s0; a0.y *= s0; a0.z *= s0; a0.w *= s0;
    a1.x *= s1; a1.y *= s1; a1.z *= s1; a1.w *= s1;
    ((float4*)(Y + (size_t)(r0 + 0) * 32))[q] = a0;
    ((float4*)(Y + (size_t)(r0 + 1) * 32))[q] = a1;
}

// ---------------- fused gather-aggregate + next-layer matmul ----------------
// Thread (n, c): gather-sum hws rows (padded CSR, conditional-free), tanh -> xout.
// MODE 1: also compute hnext[n][c] = invs[n] * sum_c' x[n][c'] * Wn[c'][c]
//         via LDS row stage + barrier + 8x ds_read_b128 broadcast.
// MODE 2: hnext[n] = invs[n] * dot(x[n,:], Wn[0:32])  (shfl_xor reduce).
// Grid is exact (NN*32/256 blocks) -> no early returns, barrier is safe.
template <int MODE>
__global__ void k_aggr_f(const int* __restrict__ rowstart, const int* __restrict__ esrc,
                         const float* __restrict__ hws, const float* __restrict__ inv_sqrt,
                         const float* __restrict__ bvec, const float* __restrict__ Wn,
                         float* __restrict__ xout, float* __restrict__ hnext) {
    __shared__ float sxr[8][32];
    int t = blockIdx.x * 256 + threadIdx.x;
    int n = t >> 5, c = t & 31;
    int e0 = rowstart[n], e1 = rowstart[n + 1];
    float a[8];
    a[0] = hws[(size_t)n * 32 + c];
#pragma unroll
    for (int k = 1; k < 8; k++) a[k] = 0.0f;
    for (int e = e0; e < e1; e += 8) {
        int4 sA = *(const int4*)(esrc + e);
        int4 sB = *(const int4*)(esrc + e + 4);
        float v0 = hws[(size_t)sA.x * 32 + c];
        float v1 = hws[(size_t)sA.y * 32 + c];
        float v2 = hws[(size_t)sA.z * 32 + c];
        float v3 = hws[(size_t)sA.w * 32 + c];
        float v4 = hws[(size_t)sB.x * 32 + c];
        float v5 = hws[(size_t)sB.y * 32 + c];
        float v6 = hws[(size_t)sB.z * 32 + c];
        float v7 = hws[(size_t)sB.w * 32 + c];
        a[0] += v0; a[1] += v1; a[2] += v2; a[3] += v3;
        a[4] += v4; a[5] += v5; a[6] += v6; a[7] += v7;
    }
    float acc = ((a[0] + a[1]) + (a[2] + a[3])) + ((a[4] + a[5]) + (a[6] + a[7]));
    float invs = inv_sqrt[n];
    float r = tanhf(fmaf(acc, invs, bvec[c]));
    xout[t] = r;
    if (MODE == 1) {
        int ln = threadIdx.x >> 5;
        sxr[ln][c] = r;
        // preload column c of Wn (32x32) into registers (after the gather loop
        // to keep loop register pressure unchanged; L2-hot after first block)
        float wcol[32];
#pragma unroll
        for (int k = 0; k < 32; k++) wcol[k] = Wn[k * 32 + c];
        __syncthreads();
        const float4* xr = (const float4*)sxr[ln];
        float h = 0.f;
#pragma unroll
        for (int j = 0; j < 8; j++) {
            float4 xq = xr[j];
            h = fmaf(xq.x, wcol[4 * j + 0], h);
            h = fmaf(xq.y, wcol[4 * j + 1], h);
            h = fmaf(xq.z, wcol[4 * j + 2], h);
            h = fmaf(xq.w, wcol[4 * j + 3], h);
        }
        hnext[t] = h * invs;
    } else {
        float v = r * Wn[c];
        v += __shfl_xor(v, 1);
        v += __shfl_xor(v, 2);
        v += __shfl_xor(v, 4);
        v += __shfl_xor(v, 8);
        v += __shfl_xor(v, 16);
        if (c == 0) hnext[n] = v * invs;
        if (t == 0) hnext[NN] = 0.f;   // pad target for k_aggr1
    }
}

// layer-4 aggregation (1 channel), padded CSR: conditional-free
__global__ void k_aggr1(const int* __restrict__ rowstart, const int* __restrict__ esrc,
                        const float* __restrict__ hws4, const float* __restrict__ inv_sqrt,
                        const float* __restrict__ b4, float* __restrict__ x4) {
    int n = blockIdx.x * 256 + threadIdx.x;
    if (n >= NN) return;
    int e0 = rowstart[n], e1 = rowstart[n + 1];
    float a[8];
    a[0] = hws4[n];
#pragma unroll
    for (int k = 1; k < 8; k++) a[k] = 0.0f;
    for (int e = e0; e < e1; e += 8) {
        int4 sA = *(const int4*)(esrc + e);
        int4 sB = *(const int4*)(esrc + e + 4);
        a[0] += hws4[sA.x]; a[1] += hws4[sA.y];
        a[2] += hws4[sA.z]; a[3] += hws4[sA.w];
        a[4] += hws4[sB.x]; a[5] += hws4[sB.y];
        a[6] += hws4[sB.z]; a[7] += hws4[sB.w];
    }
    float acc = ((a[0] + a[1]) + (a[2] + a[3])) + ((a[4] + a[5]) + (a[6] + a[7]));
    x4[n] = tanhf(fmaf(acc, inv_sqrt[n], b4[0]));
}

// ---------------- graph boundaries from sorted batch (no atomics) ----------------
__global__ void k_gbounds(const int* __restrict__ batch, int* __restrict__ starts) {
    int n = blockIdx.x * 256 + threadIdx.x;
    if (n >= NN) return;
    int bn = batch[n];
    int bp = (n == 0) ? -1 : batch[n - 1];
    for (int g = bp + 1; g <= bn; g++) starts[g] = n;
    if (n == NN - 1)
        for (int g = bn + 1; g <= NG; g++) starts[g] = NN;
}

// ---------------- merged sort-pool + CNN/MLP head, one block per graph ----------------
__global__ void k_tail(const int* __restrict__ starts,
                       const float* __restrict__ x1, const float* __restrict__ x2,
                       const float* __restrict__ x3, const float* __restrict__ x4,
                       const float* __restrict__ w5, const float* __restrict__ b5,
                       const float* __restrict__ w6, const float* __restrict__ b6,
                       const float* __restrict__ fw1, const float* __restrict__ fb1,
                       const float* __restrict__ fw2, const float* __restrict__ fb2,
                       float* __restrict__ out) {
    __shared__ float keys[1024];
    __shared__ int sel[KSEL];
    __shared__ float sP[KSEL * CCAT];
    __shared__ float s5[16 * 30];
    __shared__ float smp[16 * 15];
    __shared__ float sz[352];
    __shared__ float sh[128];
    __shared__ float sl[10];
    int g = blockIdx.x;
    int tid = threadIdx.x;
    int start = starts[g];
    int cnt = starts[g + 1] - start;
    if (cnt > 1024) cnt = 1024;
    for (int i = tid; i < cnt; i += 256) keys[i] = x4[start + i];
    __syncthreads();
    for (int i = tid; i < cnt; i += 256) {
        float ki = keys[i];
        int rank = 0;
        for (int j = 0; j < cnt; j++) {
            float kj = keys[j];
            rank += (kj > ki) || (kj == ki && j < i);  // stable desc, matches lexsort
        }
        if (rank < KSEL) sel[rank] = start + i;
    }
    __syncthreads();
    int selcnt = cnt < KSEL ? cnt : KSEL;
    for (int t = tid; t < KSEL * CCAT; t += 256) {
        int r = t / CCAT, ch = t - r * CCAT;
        float v = 0.0f;
        if (r < selcnt) {
            int node = sel[r];
            if (ch < 32)      v = x1[(size_t)node * 32 + ch];
            else if (ch < 64) v = x2[(size_t)node * 32 + ch - 32];
            else if (ch < 96) v = x3[(size_t)node * 32 + ch - 64];
            else              v = x4[node];
        }
        sP[t] = v;
    }
    __syncthreads();
    for (int t = tid; t < 16 * 30; t += 256) {
        int c = t / 30, j = t - c * 30;
        float acc = b5[c];
        for (int i = 0; i < CCAT; i++) acc = fmaf(sP[j * CCAT + i], w5[c * CCAT + i], acc);
        s5[c * 30 + j] = fmaxf(acc, 0.0f);
    }
    __syncthreads();
    for (int t = tid; t < 16 * 15; t += 256) {
        int c = t / 15, j = t - c * 15;
        smp[t] = fmaxf(s5[c * 30 + 2 * j], s5[c * 30 + 2 * j + 1]);
    }
    __syncthreads();
    for (int t = tid; t < 32 * 11; t += 256) {
        int c = t / 11, j = t - c * 11;
        float acc = b6[c];
        for (int ci = 0; ci < 16; ci++) {
#pragma unroll
            for (int k = 0; k < 5; k++)
                acc = fmaf(smp[ci * 15 + j + k], w6[(c * 16 + ci) * 5 + k], acc);
        }
        sz[t] = fmaxf(acc, 0.0f);
    }
    __syncthreads();
    if (tid < 128) {
        float acc = fb1[tid];
        for (int i = 0; i < 352; i++) acc = fmaf(sz[i], fw1[i * 128 + tid], acc);
        sh[tid] = fmaxf(acc, 0.0f);
    }
    __syncthreads();
    if (tid < 10) {
        float acc = fb2[tid];
        for (int i = 0; i < 128; i++) acc = fmaf(sh[i], fw2[i * 10 + tid], acc);
        sl[tid] = acc;
    }
    __syncthreads();
    if (tid < 10) {
        float m = -1e30f;
        for (int i = 0; i < 10; i++) m = fmaxf(m, sl[i]);
        float ssum = 0.0f;
        for (int i = 0; i < 10; i++) ssum += expf(sl[i] - m);
        out[g * 10 + tid] = sl[tid] - m - logf(ssum);
    }
}

extern "C" void kernel_launch(void* const* d_in, const int* in_sizes, int n_in,
                              void* d_out, int out_size, void* d_ws, size_t ws_size,
                              hipStream_t stream) {
    const float* x   = (const float*)d_in[0];
    const int*   ei  = (const int*)d_in[1];
    const int*   bat = (const int*)d_in[2];
    const float* W1  = (const float*)d_in[3];
    const float* b1  = (const float*)d_in[4];
    const float* W2  = (const float*)d_in[5];
    const float* b2  = (const float*)d_in[6];
    const float* W3  = (const float*)d_in[7];
    const float* b3  = (const float*)d_in[8];
    const float* W4  = (const float*)d_in[9];
    const float* b4  = (const float*)d_in[10];
    const float* w5  = (const float*)d_in[11];
    const float* b5  = (const float*)d_in[12];
    const float* w6  = (const float*)d_in[13];
    const float* b6  = (const float*)d_in[14];
    const float* fw1 = (const float*)d_in[15];
    const float* fb1 = (const float*)d_in[16];
    const float* fw2 = (const float*)d_in[17];
    const float* fb2 = (const float*)d_in[18];
    float* out = (float*)d_out;

    float* ws = (float*)d_ws;
    float* inv_sqrt = ws;                             // NN
    float* hwsA     = inv_sqrt + NN;                  // (NN+1)*32, row NN = zero pad
    float* hwsB     = hwsA + (size_t)(NN + 1) * 32;   // (NN+1)*32, row NN = zero pad
    float* x1       = hwsB + (size_t)(NN + 1) * 32;   // NN*32
    float* x2       = x1 + (size_t)NN * 32;           // NN*32
    float* x3       = x2 + (size_t)NN * 32;           // NN*32
    float* x4       = x3 + (size_t)NN * 32;           // NN
    int* rowcnt     = (int*)(x4 + NN);                // NPAD
    int* rowstart   = rowcnt + NPAD;                  // NPAD
    int* esrc       = rowstart + NPAD;                // EPADCAP
    int* bcursor    = esrc + EPADCAP;                 // NB (pad to 512)
    int* bsums      = bcursor + 512;                  // 256
    int* gstarts    = bsums + 256;                    // NG+1 (pad to 1024)
    int* ebuf       = (int*)x3;                       // NB*BCAP ints (16 MB), dead before x3 written

    const int TB = 256;
    int gN  = (NN + TB - 1) / TB;
    int gNC = (NN * 32) / TB;      // exact: 25000
    int gMM = NN / 64;             // exact: 3125

    // ---- CSR build via bucketed partition ----
    hipMemsetAsync(bcursor, 0, 512 * sizeof(int), stream);
    hipMemsetAsync(rowcnt, 0, NPAD * sizeof(int), stream);
    hipMemsetAsync(hwsA + (size_t)NN * 32, 0, 32 * sizeof(float), stream);  // zero pad rows
    hipMemsetAsync(hwsB + (size_t)NN * 32, 0, 32 * sizeof(float), stream);
    k_p1_partition<<<P1_BLKS, TB, 0, stream>>>(ei, bcursor, ebuf);
    k_p2_count<<<NB, TB, 0, stream>>>(bcursor, ebuf, rowcnt, inv_sqrt);
    k_scanA<<<SCAN_BLKS, 1024, 0, stream>>>(rowcnt, rowstart, bsums);
    k_scanB<<<1, 256, 0, stream>>>(bsums);
    k_scanC<<<SCAN_BLKS, 1024, 0, stream>>>(rowstart, bsums);
    k_p3_scatter<<<NB, TB, 0, stream>>>(bcursor, ebuf, rowstart, esrc);

    // ---- graph boundaries (sorted batch -> no atomics) ----
    k_gbounds<<<gN, TB, 0, stream>>>(bat, gstarts);

    // ---- GCN layers (fused: aggr + next-layer matmul) ----
    k_mm<128><<<gMM, TB, 0, stream>>>(x, W1, inv_sqrt, hwsA);
    k_aggr_f<1><<<gNC, TB, 0, stream>>>(rowstart, esrc, hwsA, inv_sqrt, b1, W2, x1, hwsB);
    k_aggr_f<1><<<gNC, TB, 0, stream>>>(rowstart, esrc, hwsB, inv_sqrt, b2, W3, x2, hwsA);
    k_aggr_f<2><<<gNC, TB, 0, stream>>>(rowstart, esrc, hwsA, inv_sqrt, b3, W4, x3, hwsB);
    k_aggr1<<<gN, TB, 0, stream>>>(rowstart, esrc, hwsB, inv_sqrt, b4, x4);

    // ---- merged sort-pool + head ----
    k_tail<<<NG, TB, 0, stream>>>(gstarts, x1, x2, x3, x4,
                                  w5, b5, w6, b6, fw1, fb1, fw2, fb2, out);
}